// Round 2
// baseline (2065.776 us; speedup 1.0000x reference)
//
#include <hip/hip_runtime.h>
#include <math.h>

namespace {

constexpr size_t ND = 16777216;   // B*C*P*D = 8*32*256*256
constexpr float INV_SQRT_R = 0.17677669529663689f;

enum { EPI_NONE = 0, EPI_RELU, EPI_GATE, EPI_GELU, EPI_ADDRES, EPI_TOPIC };

// ---------------- LayerNorm over last dim (256) ----------------
__global__ __launch_bounds__(256) void ln_kernel(
    const float* __restrict__ x, const float* __restrict__ sc,
    const float* __restrict__ bi, float* __restrict__ y)
{
    const size_t row = blockIdx.x;
    const int t = threadIdx.x;
    const float v = x[row * 256 + t];
    float s = v, s2 = v * v;
    #pragma unroll
    for (int o = 32; o > 0; o >>= 1) {
        s  += __shfl_xor(s, o);
        s2 += __shfl_xor(s2, o);
    }
    __shared__ float ps[4], ps2[4];
    if ((t & 63) == 0) { ps[t >> 6] = s; ps2[t >> 6] = s2; }
    __syncthreads();
    const float S  = ps[0] + ps[1] + ps[2] + ps[3];
    const float S2 = ps2[0] + ps2[1] + ps2[2] + ps2[3];
    const float mean = S * (1.0f / 256.0f);
    const float var  = S2 * (1.0f / 256.0f) - mean * mean;
    const float inv  = 1.0f / sqrtf(var + 1e-5f);
    y[row * 256 + t] = (v - mean) * inv * sc[t] + bi[t];
}

// ---------------- Generic batched GEMM ----------------
// C[m,n] = sum_k A[m,k] * (TRANSB ? W[n,k] : B[k,n])   per batch bb
// Output offset = bb*s_b + (m>>8)*s_c + (m&255)*s_p + (n>>5)*s_h + (n&31)
template<bool TRANSB, int EPI>
__global__ __launch_bounds__(256) void gemm_kernel(
    const float* __restrict__ A, const float* __restrict__ Bm, float* Cout,
    int M, int Nn, int K, size_t aStride, size_t bStride,
    size_t s_b, size_t s_c, size_t s_p, size_t s_h,
    const float* __restrict__ bias, const float* e0,
    const float* e1, const float* e2)
{
    const int bb = blockIdx.z;
    const int m0 = blockIdx.x * 64;
    const int n0 = blockIdx.y * 64;
    const float* Ab = A + (size_t)bb * aStride;
    const float* Bb = Bm + (size_t)bb * bStride;
    __shared__ float As[16][64];
    __shared__ float Bs[16][64];
    const int t = threadIdx.x;
    const int tx = t & 15, ty = t >> 4;
    float acc[4][4] = {};
    for (int k0 = 0; k0 < K; k0 += 16) {
        {
            int m = t >> 2, kk = (t & 3) << 2;
            float4 av = *(const float4*)(Ab + (size_t)(m0 + m) * K + k0 + kk);
            As[kk + 0][m] = av.x; As[kk + 1][m] = av.y;
            As[kk + 2][m] = av.z; As[kk + 3][m] = av.w;
        }
        if (TRANSB) {
            int n = t >> 2, kk = (t & 3) << 2;
            float4 bv = *(const float4*)(Bb + (size_t)(n0 + n) * K + k0 + kk);
            Bs[kk + 0][n] = bv.x; Bs[kk + 1][n] = bv.y;
            Bs[kk + 2][n] = bv.z; Bs[kk + 3][n] = bv.w;
        } else {
            int kk = t >> 4, nn = (t & 15) << 2;
            *(float4*)&Bs[kk][nn] = *(const float4*)(Bb + (size_t)(k0 + kk) * Nn + n0 + nn);
        }
        __syncthreads();
        #pragma unroll
        for (int k = 0; k < 16; ++k) {
            float4 a4 = *(const float4*)&As[k][ty << 2];
            float4 b4 = *(const float4*)&Bs[k][tx << 2];
            float av[4] = {a4.x, a4.y, a4.z, a4.w};
            float bv[4] = {b4.x, b4.y, b4.z, b4.w};
            #pragma unroll
            for (int i = 0; i < 4; ++i)
                #pragma unroll
                for (int j = 0; j < 4; ++j)
                    acc[i][j] += av[i] * bv[j];
        }
        __syncthreads();
    }
    #pragma unroll
    for (int i = 0; i < 4; ++i) {
        const int m  = m0 + (ty << 2) + i;
        const int nb = n0 + (tx << 2);
        const size_t off = (size_t)bb * s_b + (size_t)(m >> 8) * s_c
                         + (size_t)(m & 255) * s_p + (size_t)(nb >> 5) * s_h + (nb & 31);
        float r[4];
        #pragma unroll
        for (int j = 0; j < 4; ++j) r[j] = acc[i][j];
        if (EPI == EPI_RELU) {
            #pragma unroll
            for (int j = 0; j < 4; ++j) r[j] = fmaxf(r[j], 0.0f);
        } else if (EPI == EPI_GELU) {
            #pragma unroll
            for (int j = 0; j < 4; ++j) {
                float xv = r[j] + bias[nb + j];
                r[j] = 0.5f * xv * (1.0f + erff(xv * 0.7071067811865475f));
            }
        } else if (EPI == EPI_GATE) {
            float4 z  = *(const float4*)(e0 + off);
            float4 u  = *(const float4*)(e1 + off);
            float4 ms = *(const float4*)(e2 + off);
            float zz[4] = {z.x, z.y, z.z, z.w};
            float uu[4] = {u.x, u.y, u.z, u.w};
            float mm[4] = {ms.x, ms.y, ms.z, ms.w};
            #pragma unroll
            for (int j = 0; j < 4; ++j) {
                float g = 1.0f / (1.0f + __expf(-(r[j] + bias[nb + j])));
                r[j] = g * zz[j] + (1.0f - g) * (uu[j] + mm[j]);
            }
        } else if (EPI == EPI_ADDRES) {
            float4 z = *(const float4*)(e0 + off);
            float zz[4] = {z.x, z.y, z.z, z.w};
            #pragma unroll
            for (int j = 0; j < 4; ++j) r[j] += bias[nb + j] + zz[j];
        } else if (EPI == EPI_TOPIC) {
            float inv = 1.0f / fmaxf(e0[(size_t)bb * M + m], 1e-6f);
            float4 ms = *(const float4*)(e2 + off);
            float mm[4] = {ms.x, ms.y, ms.z, ms.w};
            #pragma unroll
            for (int j = 0; j < 4; ++j) r[j] = mm[j] + r[j] * inv;
        }
        *(float4*)(Cout + off) = make_float4(r[0], r[1], r[2], r[3]);
    }
}

// ---------------- Time attention: per (b*c, 32-row tile) ----------------
// qu/qv layout [bc][h][p][r]; writes head-averaged softmax Abar [bc][p][q]
__global__ __launch_bounds__(256) void time_attn_kernel(
    const float* __restrict__ qu, const float* __restrict__ qv, float* __restrict__ abar)
{
    const int bc = blockIdx.x;
    const int p0 = blockIdx.y * 32;
    const float* quB = qu + (size_t)bc * 65536;
    const float* qvB = qv + (size_t)bc * 65536;
    __shared__ float qus[8][32][32];
    __shared__ float qvt[32][256];
    const int t = threadIdx.x;
    {
        const int row = t >> 3, r4 = (t & 7) << 2;
        #pragma unroll
        for (int h = 0; h < 8; ++h) {
            float4 v = *(const float4*)(quB + h * 8192 + (p0 + row) * 32 + r4);
            *(float4*)&qus[h][row][r4] = v;
        }
    }
    const int w8 = (t >> 6) << 3;       // wave owns rows w8..w8+7 (all 256 q per wave)
    const int q0 = (t & 63) << 2;
    float acc[8][4] = {};
    for (int h = 0; h < 8; ++h) {
        __syncthreads();
        {   // stage qv^T for this head: qvt[r][q]
            const float4* src = (const float4*)(qvB + h * 8192 + t * 32);
            #pragma unroll
            for (int r4 = 0; r4 < 8; ++r4) {
                float4 v = src[r4];
                qvt[r4 * 4 + 0][t] = v.x; qvt[r4 * 4 + 1][t] = v.y;
                qvt[r4 * 4 + 2][t] = v.z; qvt[r4 * 4 + 3][t] = v.w;
            }
        }
        __syncthreads();
        float s[8][4];
        #pragma unroll
        for (int rr = 0; rr < 8; ++rr) { s[rr][0] = s[rr][1] = s[rr][2] = s[rr][3] = 0.f; }
        #pragma unroll
        for (int r = 0; r < 32; ++r) {
            float4 vv = *(const float4*)&qvt[r][q0];
            #pragma unroll
            for (int rr = 0; rr < 8; ++rr) {
                float a = qus[h][w8 + rr][r];
                s[rr][0] += a * vv.x; s[rr][1] += a * vv.y;
                s[rr][2] += a * vv.z; s[rr][3] += a * vv.w;
            }
        }
        #pragma unroll
        for (int rr = 0; rr < 8; ++rr) {
            float s0 = s[rr][0] * INV_SQRT_R, s1 = s[rr][1] * INV_SQRT_R;
            float s2 = s[rr][2] * INV_SQRT_R, s3 = s[rr][3] * INV_SQRT_R;
            float mx = fmaxf(fmaxf(s0, s1), fmaxf(s2, s3));
            #pragma unroll
            for (int o = 32; o > 0; o >>= 1) mx = fmaxf(mx, __shfl_xor(mx, o));
            float e0x = __expf(s0 - mx), e1x = __expf(s1 - mx);
            float e2x = __expf(s2 - mx), e3x = __expf(s3 - mx);
            float sum = e0x + e1x + e2x + e3x;
            #pragma unroll
            for (int o = 32; o > 0; o >>= 1) sum += __shfl_xor(sum, o);
            float inv = 0.125f / sum;
            acc[rr][0] += e0x * inv; acc[rr][1] += e1x * inv;
            acc[rr][2] += e2x * inv; acc[rr][3] += e3x * inv;
        }
    }
    #pragma unroll
    for (int rr = 0; rr < 8; ++rr) {
        *(float4*)(abar + (size_t)bc * 65536 + (size_t)(p0 + w8 + rr) * 256 + q0)
            = make_float4(acc[rr][0], acc[rr][1], acc[rr][2], acc[rr][3]);
    }
}

// ---------------- Fused channel attention + PV: one block per (b,p) ----------------
// quc/qvc layout [b][p][h][c][r]; msum[b,c,p,:] += (1/8) sum_h sum_f attn_h[c,f]*qzn[b,f,p,:]
__global__ __launch_bounds__(256) void chan_fused_kernel(
    const float* __restrict__ quc, const float* __restrict__ qvc,
    const float* __restrict__ qzn, float* msum)
{
    const int bp = blockIdx.x;
    const int b = bp >> 8, p = bp & 255;
    const float* quB = quc + (size_t)bp * 8192;
    const float* qvB = qvc + (size_t)bp * 8192;
    __shared__ float U[16896];          // qus[8448] + qvs[8448]; later bt[32*256]
    __shared__ float ab[32 * 33];
    float* qus = U;
    float* qvs = U + 8448;
    const int t = threadIdx.x;
    #pragma unroll
    for (int i = 0; i < 8; ++i) {
        int fi = i * 256 + t;
        float4 a = ((const float4*)quB)[fi];
        float4 bv = ((const float4*)qvB)[fi];
        int e = fi << 2;
        int base = ((e >> 10) * 32 + ((e >> 5) & 31)) * 33 + (e & 31);
        qus[base + 0] = a.x; qus[base + 1] = a.y; qus[base + 2] = a.z; qus[base + 3] = a.w;
        qvs[base + 0] = bv.x; qvs[base + 1] = bv.y; qvs[base + 2] = bv.z; qvs[base + 3] = bv.w;
    }
    __syncthreads();
    const int c = t >> 3, j = t & 7;    // 8-lane group per row c
    float acc[4] = {0.f, 0.f, 0.f, 0.f};
    for (int h = 0; h < 8; ++h) {
        float qur[32];
        #pragma unroll
        for (int r = 0; r < 32; ++r) qur[r] = qus[(h * 32 + c) * 33 + r];
        float s[4];
        #pragma unroll
        for (int jj = 0; jj < 4; ++jj) {
            int f = j * 4 + jj;
            const float* qvR = &qvs[(h * 32 + f) * 33];
            float a = 0.f;
            #pragma unroll
            for (int r = 0; r < 32; ++r) a += qur[r] * qvR[r];
            s[jj] = a * INV_SQRT_R;
        }
        float mx = fmaxf(fmaxf(s[0], s[1]), fmaxf(s[2], s[3]));
        mx = fmaxf(mx, __shfl_xor(mx, 1));
        mx = fmaxf(mx, __shfl_xor(mx, 2));
        mx = fmaxf(mx, __shfl_xor(mx, 4));
        float e0x = __expf(s[0] - mx), e1x = __expf(s[1] - mx);
        float e2x = __expf(s[2] - mx), e3x = __expf(s[3] - mx);
        float sum = e0x + e1x + e2x + e3x;
        sum += __shfl_xor(sum, 1);
        sum += __shfl_xor(sum, 2);
        sum += __shfl_xor(sum, 4);
        float inv = 0.125f / sum;
        acc[0] += e0x * inv; acc[1] += e1x * inv; acc[2] += e2x * inv; acc[3] += e3x * inv;
    }
    #pragma unroll
    for (int jj = 0; jj < 4; ++jj) ab[c * 33 + j * 4 + jj] = acc[jj];
    __syncthreads();                    // all attn reads of U done; ab complete
    float* bt = U;                      // reuse U for qzn rows [f][d]
    #pragma unroll 4
    for (int f = 0; f < 32; ++f)
        bt[f * 256 + t] = qzn[((size_t)(b * 32 + f) * 256 + p) * 256 + t];
    __syncthreads();
    for (int c2 = 0; c2 < 32; c2 += 2) {
        float a0 = 0.f, a1 = 0.f;
        #pragma unroll
        for (int f = 0; f < 32; ++f) {
            float v = bt[f * 256 + t];
            a0 += ab[c2 * 33 + f] * v;
            a1 += ab[(c2 + 1) * 33 + f] * v;
        }
        size_t off = ((size_t)(b * 32 + c2) * 256 + p) * 256 + t;
        msum[off] += a0;
        msum[off + 65536] += a1;
    }
}

// ---------------- Row L1 sums of qg [rows][512] ----------------
__global__ __launch_bounds__(256) void rowsum_kernel(
    const float* __restrict__ qg, float* __restrict__ rs)
{
    const size_t row = blockIdx.x;
    const int t = threadIdx.x;
    float v = qg[row * 512 + t] + qg[row * 512 + 256 + t];
    #pragma unroll
    for (int o = 32; o > 0; o >>= 1) v += __shfl_xor(v, o);
    __shared__ float ps[4];
    if ((t & 63) == 0) ps[t >> 6] = v;
    __syncthreads();
    if (t == 0) rs[row] = ps[0] + ps[1] + ps[2] + ps[3];
}

} // namespace

extern "C" void kernel_launch(void* const* d_in, const int* in_sizes, int n_in,
                              void* d_out, int out_size, void* d_ws, size_t ws_size,
                              hipStream_t stream)
{
    (void)in_sizes; (void)n_in; (void)out_size; (void)ws_size;
    const float* qz     = (const float*)d_in[0];
    const float* unary  = (const float*)d_in[1];
    const float* time_u = (const float*)d_in[2];
    const float* time_v = (const float*)d_in[3];
    const float* chan_u = (const float*)d_in[4];
    const float* chan_v = (const float*)d_in[5];
    const float* topic  = (const float*)d_in[6];
    const float* nsc    = (const float*)d_in[7];
    const float* nbi    = (const float*)d_in[8];
    const float* gate_w = (const float*)d_in[9];
    const float* gate_b = (const float*)d_in[10];
    const float* w1     = (const float*)d_in[11];
    const float* b1     = (const float*)d_in[12];
    const float* w2     = (const float*)d_in[13];
    const float* b2     = (const float*)d_in[14];

    // Tight workspace plan: only 3 x 64MB units in d_ws; d_out doubles as scratch.
    float* W0  = (float*)d_ws;            // qzn -> rowsums -> h0
    float* W1  = W0 + ND;                 // time_u proj -> msum -> h1
    float* W2  = W0 + 2 * ND;             // time_v proj -> chan_u proj -> qg_lo -> qz2
    float* OUT = (float*)d_out;           // abar_t -> chan_v proj -> qg_hi -> final out

    dim3 blk(256);

    // 1) qz_n = LN(qz) -> W0
    ln_kernel<<<65536, blk, 0, stream>>>(qz, nsc, nbi, W0);

    // 2) time projections -> [b][c][h][p][r]
    gemm_kernel<true, EPI_NONE><<<dim3(128, 4, 8), blk, 0, stream>>>(
        W0, time_u, W1, 8192, 256, 256, 2097152, 65536,
        2097152, 65536, 32, 8192, nullptr, nullptr, nullptr, nullptr);
    gemm_kernel<true, EPI_NONE><<<dim3(128, 4, 8), blk, 0, stream>>>(
        W0, time_v, W2, 8192, 256, 256, 2097152, 65536,
        2097152, 65536, 32, 8192, nullptr, nullptr, nullptr, nullptr);

    // 3) head-averaged time attention -> Abar [bc][p][q] in OUT (scratch)
    time_attn_kernel<<<dim3(256, 8), blk, 0, stream>>>(W1, W2, OUT);

    // 4) msum = m_t = Abar @ qz_n  -> W1 (time_u proj dead)
    gemm_kernel<false, EPI_NONE><<<dim3(4, 4, 256), blk, 0, stream>>>(
        OUT, W0, W1, 256, 256, 256, 65536, 65536,
        65536, 0, 256, 32, nullptr, nullptr, nullptr, nullptr);

    // 5) channel projections -> [b][p][h][c][r]: cu -> W2, cv -> OUT
    gemm_kernel<true, EPI_NONE><<<dim3(128, 4, 8), blk, 0, stream>>>(
        W0, chan_u, W2, 8192, 256, 256, 2097152, 65536,
        2097152, 32, 8192, 1024, nullptr, nullptr, nullptr, nullptr);
    gemm_kernel<true, EPI_NONE><<<dim3(128, 4, 8), blk, 0, stream>>>(
        W0, chan_v, OUT, 8192, 256, 256, 2097152, 65536,
        2097152, 32, 8192, 1024, nullptr, nullptr, nullptr, nullptr);

    // 6) fused channel attention + PV: msum(W1) += m_c
    chan_fused_kernel<<<2048, blk, 0, stream>>>(W2, OUT, W0, W1);

    // 7) topic factor, split into batch halves (qg_lo->W2, qg_hi->OUT)
    gemm_kernel<true, EPI_RELU><<<dim3(128, 8, 4), blk, 0, stream>>>(
        W0, topic, W2, 8192, 512, 256, 2097152, 131072,
        4194304, 131072, 512, 32, nullptr, nullptr, nullptr, nullptr);
    gemm_kernel<true, EPI_RELU><<<dim3(128, 8, 4), blk, 0, stream>>>(
        W0 + 4 * 2097152, topic + 4 * 131072, OUT, 8192, 512, 256, 2097152, 131072,
        4194304, 131072, 512, 32, nullptr, nullptr, nullptr, nullptr);
    // rowsums -> W0 (qzn dead after the two relu GEMMs)
    rowsum_kernel<<<32768, blk, 0, stream>>>(W2, W0);
    rowsum_kernel<<<32768, blk, 0, stream>>>(OUT, W0 + 32768);
    // msum += (qg / rowsum) @ topic
    gemm_kernel<false, EPI_TOPIC><<<dim3(128, 4, 4), blk, 0, stream>>>(
        W2, topic, W1, 8192, 256, 512, 4194304, 131072,
        2097152, 65536, 256, 32, nullptr, W0, nullptr, W1);
    gemm_kernel<false, EPI_TOPIC><<<dim3(128, 4, 4), blk, 0, stream>>>(
        OUT, topic + 4 * 131072, W1 + 4 * 2097152, 8192, 256, 512, 4194304, 131072,
        2097152, 65536, 256, 32, nullptr, W0 + 32768, nullptr, W1 + 4 * 2097152);

    // 8) gate + residual combine -> qz2 = W2
    gemm_kernel<true, EPI_GATE><<<dim3(1024, 4, 1), blk, 0, stream>>>(
        qz, gate_w, W2, 65536, 256, 256, 0, 0,
        0, 65536, 256, 32, gate_b, qz, unary, W1);

    // 9) output MLP with shared LN: h0=W0, h1=W1, final -> OUT
    ln_kernel<<<65536, blk, 0, stream>>>(W2, nsc, nbi, W0);
    gemm_kernel<true, EPI_GELU><<<dim3(1024, 4, 1), blk, 0, stream>>>(
        W0, w1, W1, 65536, 256, 256, 0, 0,
        0, 65536, 256, 32, b1, nullptr, nullptr, nullptr);
    gemm_kernel<true, EPI_ADDRES><<<dim3(1024, 4, 1), blk, 0, stream>>>(
        W1, w2, OUT, 65536, 256, 256, 0, 0,
        0, 65536, 256, 32, b2, W2, nullptr, nullptr);
}

// Round 4
// 1123.118 us; speedup vs baseline: 1.8393x; 1.8393x over previous
//
#include <hip/hip_runtime.h>
#include <math.h>

namespace {

constexpr size_t ND = 16777216;   // B*C*P*D = 8*32*256*256
constexpr float INV_SQRT_R = 0.17677669529663689f;

typedef __attribute__((ext_vector_type(8))) __bf16 bf16x8;
typedef __attribute__((ext_vector_type(4))) float f32x4;

enum { EPI_NONE = 0, EPI_RELU, EPI_GATE, EPI_GELU, EPI_ADDRES, EPI_TOPIC };

// ---------------- LayerNorm over last dim (256) ----------------
__global__ __launch_bounds__(256) void ln_kernel(
    const float* __restrict__ x, const float* __restrict__ sc,
    const float* __restrict__ bi, float* __restrict__ y)
{
    const size_t row = blockIdx.x;
    const int t = threadIdx.x;
    const float v = x[row * 256 + t];
    float s = v, s2 = v * v;
    #pragma unroll
    for (int o = 32; o > 0; o >>= 1) {
        s  += __shfl_xor(s, o);
        s2 += __shfl_xor(s2, o);
    }
    __shared__ float ps[4], ps2[4];
    if ((t & 63) == 0) { ps[t >> 6] = s; ps2[t >> 6] = s2; }
    __syncthreads();
    const float S  = ps[0] + ps[1] + ps[2] + ps[3];
    const float S2 = ps2[0] + ps2[1] + ps2[2] + ps2[3];
    const float mean = S * (1.0f / 256.0f);
    const float var  = S2 * (1.0f / 256.0f) - mean * mean;
    const float inv  = 1.0f / sqrtf(var + 1e-5f);
    y[row * 256 + t] = (v - mean) * inv * sc[t] + bi[t];
}

// ---------------- Batched fp32 transpose: dst[c][r] = src[r][c] ----------------
__global__ __launch_bounds__(256) void tpose_kernel(
    const float* __restrict__ src, float* __restrict__ dst, int R, int C)
{
    const size_t bz = blockIdx.z;
    src += bz * (size_t)R * C;
    dst += bz * (size_t)R * C;
    __shared__ float tile[32][33];
    const int r0 = blockIdx.x * 32, c0 = blockIdx.y * 32;
    const int tx = threadIdx.x & 31, ty = threadIdx.x >> 5;
    #pragma unroll
    for (int i = 0; i < 32; i += 8)
        tile[ty + i][tx] = src[(size_t)(r0 + ty + i) * C + c0 + tx];
    __syncthreads();
    #pragma unroll
    for (int i = 0; i < 32; i += 8)
        dst[(size_t)(c0 + ty + i) * R + r0 + tx] = tile[tx][ty + i];
}

// ---------------- MFMA bf16 GEMM: C[m,n] = sum_k A[m,k]*B[n,k], ld = K ----------------
// 128x128 tile, BK=32, 4 waves (2x2), per-wave 64x64 (4x4 frags of 16x16x32).
// Output offset = bb*s_b + (m>>8)*s_c + (m&255)*s_p + (n>>5)*s_h + (n&31)
template<int EPI>
__global__ __launch_bounds__(256) void mgemm_kernel(
    const float* __restrict__ A, const float* __restrict__ Bm, float* __restrict__ Cout,
    int K, size_t aStride, size_t bStride,
    size_t s_b, size_t s_c, size_t s_p, size_t s_h, int Mrows,
    const float* __restrict__ bias, const float* __restrict__ e0,
    const float* __restrict__ e1, const float* __restrict__ e2)
{
    const int bb = blockIdx.z;
    const int m0 = blockIdx.x * 128;
    const int n0 = blockIdx.y * 128;
    const float* Ab = A + (size_t)bb * aStride;
    const float* Bb = Bm + (size_t)bb * bStride;
    __shared__ __align__(16) __bf16 As[128][40];   // pad 40: conflict-free b128 reads
    __shared__ __align__(16) __bf16 Bs[128][40];
    const int t = threadIdx.x;
    const int lane = t & 63;
    const int wid = t >> 6;
    const int wr = wid >> 1, wc = wid & 1;
    const int l15 = lane & 15, lg = lane >> 4;

    f32x4 acc[4][4] = {};

    for (int k0 = 0; k0 < K; k0 += 32) {
        #pragma unroll
        for (int i = 0; i < 2; ++i) {
            const int slot = i * 256 + t;          // 0..511
            const int row = slot >> 2;
            const int k8 = (slot & 3) << 3;
            {
                const float* src = Ab + (size_t)(m0 + row) * K + k0 + k8;
                float4 v0 = *(const float4*)src;
                float4 v1 = *(const float4*)(src + 4);
                bf16x8 pk;
                pk[0] = (__bf16)v0.x; pk[1] = (__bf16)v0.y; pk[2] = (__bf16)v0.z; pk[3] = (__bf16)v0.w;
                pk[4] = (__bf16)v1.x; pk[5] = (__bf16)v1.y; pk[6] = (__bf16)v1.z; pk[7] = (__bf16)v1.w;
                *(bf16x8*)&As[row][k8] = pk;
            }
            {
                const float* src = Bb + (size_t)(n0 + row) * K + k0 + k8;
                float4 v0 = *(const float4*)src;
                float4 v1 = *(const float4*)(src + 4);
                bf16x8 pk;
                pk[0] = (__bf16)v0.x; pk[1] = (__bf16)v0.y; pk[2] = (__bf16)v0.z; pk[3] = (__bf16)v0.w;
                pk[4] = (__bf16)v1.x; pk[5] = (__bf16)v1.y; pk[6] = (__bf16)v1.z; pk[7] = (__bf16)v1.w;
                *(bf16x8*)&Bs[row][k8] = pk;
            }
        }
        __syncthreads();
        bf16x8 af[4], bfr[4];
        #pragma unroll
        for (int i = 0; i < 4; ++i)
            af[i] = *(const bf16x8*)&As[wr * 64 + i * 16 + l15][lg * 8];
        #pragma unroll
        for (int j = 0; j < 4; ++j)
            bfr[j] = *(const bf16x8*)&Bs[wc * 64 + j * 16 + l15][lg * 8];
        #pragma unroll
        for (int i = 0; i < 4; ++i)
            #pragma unroll
            for (int j = 0; j < 4; ++j)
                acc[i][j] = __builtin_amdgcn_mfma_f32_16x16x32_bf16(af[i], bfr[j], acc[i][j], 0, 0, 0);
        __syncthreads();
    }

    // Epilogue: lane's element (i,j,r): m = m0+wr*64+i*16+lg*4+r, n = n0+wc*64+j*16+l15
    #pragma unroll
    for (int j = 0; j < 4; ++j) {
        const int n = n0 + wc * 64 + j * 16 + l15;
        const size_t offn = (size_t)(n >> 5) * s_h + (n & 31);
        float bn = 0.0f;
        if (EPI == EPI_GELU || EPI == EPI_GATE || EPI == EPI_ADDRES) bn = bias[n];
        #pragma unroll
        for (int i = 0; i < 4; ++i) {
            #pragma unroll
            for (int r = 0; r < 4; ++r) {
                const int m = m0 + wr * 64 + i * 16 + lg * 4 + r;
                const size_t off = (size_t)bb * s_b + (size_t)(m >> 8) * s_c
                                 + (size_t)(m & 255) * s_p + offn;
                float v = acc[i][j][r];
                if (EPI == EPI_RELU) {
                    v = fmaxf(v, 0.0f);
                } else if (EPI == EPI_GELU) {
                    float x = v + bn;
                    v = 0.5f * x * (1.0f + erff(x * 0.7071067811865475f));
                } else if (EPI == EPI_GATE) {
                    float g = 1.0f / (1.0f + __expf(-(v + bn)));
                    v = g * e0[off] + (1.0f - g) * (e1[off] + e2[off]);
                } else if (EPI == EPI_ADDRES) {
                    v += bn + e0[off];
                } else if (EPI == EPI_TOPIC) {
                    float inv = 1.0f / fmaxf(e0[(size_t)bb * Mrows + m], 1e-6f);
                    v = e2[off] + v * inv;
                }
                Cout[off] = v;
            }
        }
    }
}

// ---------------- Time attention: per (b*c, 32-row tile) ----------------
// qu/qv layout [bc][h][p][r]; writes head-averaged softmax Abar [bc][p][q]
__global__ __launch_bounds__(256) void time_attn_kernel(
    const float* __restrict__ qu, const float* __restrict__ qv, float* __restrict__ abar)
{
    const int bc = blockIdx.x;
    const int p0 = blockIdx.y * 32;
    const float* quB = qu + (size_t)bc * 65536;
    const float* qvB = qv + (size_t)bc * 65536;
    __shared__ float qus[8][32][32];
    __shared__ float qvt[32][256];
    const int t = threadIdx.x;
    {
        const int row = t >> 3, r4 = (t & 7) << 2;
        #pragma unroll
        for (int h = 0; h < 8; ++h) {
            float4 v = *(const float4*)(quB + h * 8192 + (p0 + row) * 32 + r4);
            *(float4*)&qus[h][row][r4] = v;
        }
    }
    const int w8 = (t >> 6) << 3;       // wave owns rows w8..w8+7 (all 256 q per wave)
    const int q0 = (t & 63) << 2;
    float acc[8][4] = {};
    for (int h = 0; h < 8; ++h) {
        __syncthreads();
        {   // stage qv^T for this head: qvt[r][q]
            const float4* src = (const float4*)(qvB + h * 8192 + t * 32);
            #pragma unroll
            for (int r4 = 0; r4 < 8; ++r4) {
                float4 v = src[r4];
                qvt[r4 * 4 + 0][t] = v.x; qvt[r4 * 4 + 1][t] = v.y;
                qvt[r4 * 4 + 2][t] = v.z; qvt[r4 * 4 + 3][t] = v.w;
            }
        }
        __syncthreads();
        float s[8][4];
        #pragma unroll
        for (int rr = 0; rr < 8; ++rr) { s[rr][0] = s[rr][1] = s[rr][2] = s[rr][3] = 0.f; }
        #pragma unroll
        for (int r = 0; r < 32; ++r) {
            float4 vv = *(const float4*)&qvt[r][q0];
            #pragma unroll
            for (int rr = 0; rr < 8; ++rr) {
                float a = qus[h][w8 + rr][r];
                s[rr][0] += a * vv.x; s[rr][1] += a * vv.y;
                s[rr][2] += a * vv.z; s[rr][3] += a * vv.w;
            }
        }
        #pragma unroll
        for (int rr = 0; rr < 8; ++rr) {
            float s0 = s[rr][0] * INV_SQRT_R, s1 = s[rr][1] * INV_SQRT_R;
            float s2 = s[rr][2] * INV_SQRT_R, s3 = s[rr][3] * INV_SQRT_R;
            float mx = fmaxf(fmaxf(s0, s1), fmaxf(s2, s3));
            #pragma unroll
            for (int o = 32; o > 0; o >>= 1) mx = fmaxf(mx, __shfl_xor(mx, o));
            float e0x = __expf(s0 - mx), e1x = __expf(s1 - mx);
            float e2x = __expf(s2 - mx), e3x = __expf(s3 - mx);
            float sum = e0x + e1x + e2x + e3x;
            #pragma unroll
            for (int o = 32; o > 0; o >>= 1) sum += __shfl_xor(sum, o);
            float inv = 0.125f / sum;
            acc[rr][0] += e0x * inv; acc[rr][1] += e1x * inv;
            acc[rr][2] += e2x * inv; acc[rr][3] += e3x * inv;
        }
    }
    #pragma unroll
    for (int rr = 0; rr < 8; ++rr) {
        *(float4*)(abar + (size_t)bc * 65536 + (size_t)(p0 + w8 + rr) * 256 + q0)
            = make_float4(acc[rr][0], acc[rr][1], acc[rr][2], acc[rr][3]);
    }
}

// ---------------- Fused channel attention + PV: one block per (b,p) ----------------
__global__ __launch_bounds__(256) void chan_fused_kernel(
    const float* __restrict__ quc, const float* __restrict__ qvc,
    const float* __restrict__ qzn, float* msum)
{
    const int bp = blockIdx.x;
    const int b = bp >> 8, p = bp & 255;
    const float* quB = quc + (size_t)bp * 8192;
    const float* qvB = qvc + (size_t)bp * 8192;
    __shared__ float U[16896];          // qus[8448] + qvs[8448]; later bt[32*256]
    __shared__ float ab[32 * 33];
    float* qus = U;
    float* qvs = U + 8448;
    const int t = threadIdx.x;
    #pragma unroll
    for (int i = 0; i < 8; ++i) {
        int fi = i * 256 + t;
        float4 a = ((const float4*)quB)[fi];
        float4 bv = ((const float4*)qvB)[fi];
        int e = fi << 2;
        int base = ((e >> 10) * 32 + ((e >> 5) & 31)) * 33 + (e & 31);
        qus[base + 0] = a.x; qus[base + 1] = a.y; qus[base + 2] = a.z; qus[base + 3] = a.w;
        qvs[base + 0] = bv.x; qvs[base + 1] = bv.y; qvs[base + 2] = bv.z; qvs[base + 3] = bv.w;
    }
    __syncthreads();
    const int c = t >> 3, j = t & 7;    // 8-lane group per row c
    float acc[4] = {0.f, 0.f, 0.f, 0.f};
    for (int h = 0; h < 8; ++h) {
        float qur[32];
        #pragma unroll
        for (int r = 0; r < 32; ++r) qur[r] = qus[(h * 32 + c) * 33 + r];
        float s[4];
        #pragma unroll
        for (int jj = 0; jj < 4; ++jj) {
            int f = j * 4 + jj;
            const float* qvR = &qvs[(h * 32 + f) * 33];
            float a = 0.f;
            #pragma unroll
            for (int r = 0; r < 32; ++r) a += qur[r] * qvR[r];
            s[jj] = a * INV_SQRT_R;
        }
        float mx = fmaxf(fmaxf(s[0], s[1]), fmaxf(s[2], s[3]));
        mx = fmaxf(mx, __shfl_xor(mx, 1));
        mx = fmaxf(mx, __shfl_xor(mx, 2));
        mx = fmaxf(mx, __shfl_xor(mx, 4));
        float e0x = __expf(s[0] - mx), e1x = __expf(s[1] - mx);
        float e2x = __expf(s[2] - mx), e3x = __expf(s[3] - mx);
        float sum = e0x + e1x + e2x + e3x;
        sum += __shfl_xor(sum, 1);
        sum += __shfl_xor(sum, 2);
        sum += __shfl_xor(sum, 4);
        float inv = 0.125f / sum;
        acc[0] += e0x * inv; acc[1] += e1x * inv; acc[2] += e2x * inv; acc[3] += e3x * inv;
    }
    #pragma unroll
    for (int jj = 0; jj < 4; ++jj) ab[c * 33 + j * 4 + jj] = acc[jj];
    __syncthreads();                    // all attn reads of U done; ab complete
    float* bt = U;                      // reuse U for qzn rows [f][d]
    #pragma unroll 4
    for (int f = 0; f < 32; ++f)
        bt[f * 256 + t] = qzn[((size_t)(b * 32 + f) * 256 + p) * 256 + t];
    __syncthreads();
    for (int c2 = 0; c2 < 32; c2 += 2) {
        float a0 = 0.f, a1 = 0.f;
        #pragma unroll
        for (int f = 0; f < 32; ++f) {
            float v = bt[f * 256 + t];
            a0 += ab[c2 * 33 + f] * v;
            a1 += ab[(c2 + 1) * 33 + f] * v;
        }
        size_t off = ((size_t)(b * 32 + c2) * 256 + p) * 256 + t;
        msum[off] += a0;
        msum[off + 65536] += a1;
    }
}

// ---------------- Row L1 sums of qg [rows][512] ----------------
__global__ __launch_bounds__(256) void rowsum_kernel(
    const float* __restrict__ qg, float* __restrict__ rs)
{
    const size_t row = blockIdx.x;
    const int t = threadIdx.x;
    float v = qg[row * 512 + t] + qg[row * 512 + 256 + t];
    #pragma unroll
    for (int o = 32; o > 0; o >>= 1) v += __shfl_xor(v, o);
    __shared__ float ps[4];
    if ((t & 63) == 0) ps[t >> 6] = v;
    __syncthreads();
    if (t == 0) rs[row] = ps[0] + ps[1] + ps[2] + ps[3];
}

} // namespace

extern "C" void kernel_launch(void* const* d_in, const int* in_sizes, int n_in,
                              void* d_out, int out_size, void* d_ws, size_t ws_size,
                              hipStream_t stream)
{
    (void)in_sizes; (void)n_in; (void)out_size; (void)ws_size;
    const float* qz     = (const float*)d_in[0];
    const float* unary  = (const float*)d_in[1];
    const float* time_u = (const float*)d_in[2];
    const float* time_v = (const float*)d_in[3];
    const float* chan_u = (const float*)d_in[4];
    const float* chan_v = (const float*)d_in[5];
    const float* topic  = (const float*)d_in[6];
    const float* nsc    = (const float*)d_in[7];
    const float* nbi    = (const float*)d_in[8];
    const float* gate_w = (const float*)d_in[9];
    const float* gate_b = (const float*)d_in[10];
    const float* w1     = (const float*)d_in[11];
    const float* b1     = (const float*)d_in[12];
    const float* w2     = (const float*)d_in[13];
    const float* b2     = (const float*)d_in[14];

    // 3 x 64MB units in d_ws; d_out doubles as a 4th scratch unit.
    float* W0  = (float*)d_ws;            // qzn -> rowsums+topicT -> h0
    float* W1  = W0 + ND;                 // tu proj -> qznT -> cu proj -> qg_lo -> h1
    float* W2  = W0 + 2 * ND;             // tv proj -> msum -> qz2(in place)
    float* OUT = (float*)d_out;           // abar_t -> cv proj -> qg_hi -> final out

    dim3 blk(256);

    // 1) qz_n = LN(qz) -> W0
    ln_kernel<<<65536, blk, 0, stream>>>(qz, nsc, nbi, W0);

    // 2) time projections -> [b][c][h][p][r]
    mgemm_kernel<EPI_NONE><<<dim3(64, 2, 8), blk, 0, stream>>>(
        W0, time_u, W1, 256, 2097152, 65536,
        2097152, 65536, 32, 8192, 0, nullptr, nullptr, nullptr, nullptr);
    mgemm_kernel<EPI_NONE><<<dim3(64, 2, 8), blk, 0, stream>>>(
        W0, time_v, W2, 256, 2097152, 65536,
        2097152, 65536, 32, 8192, 0, nullptr, nullptr, nullptr, nullptr);

    // 3) head-averaged time attention -> Abar [bc][p][q] in OUT
    time_attn_kernel<<<dim3(256, 8), blk, 0, stream>>>(W1, W2, OUT);

    // 4) qznT[bc][d][p] -> W1 (tu proj dead). 256 batches of 256x256 (FIX: was 2048)
    tpose_kernel<<<dim3(8, 8, 256), blk, 0, stream>>>(W0, W1, 256, 256);

    // 5) msum = m_t = Abar @ qzn -> W2 (tv proj dead); B = qznT per bc
    mgemm_kernel<EPI_NONE><<<dim3(2, 2, 256), blk, 0, stream>>>(
        OUT, W1, W2, 256, 65536, 65536,
        65536, 0, 256, 32, 0, nullptr, nullptr, nullptr, nullptr);

    // 6) channel projections -> [b][p][h][c][r]: cu -> W1, cv -> OUT
    mgemm_kernel<EPI_NONE><<<dim3(64, 2, 8), blk, 0, stream>>>(
        W0, chan_u, W1, 256, 2097152, 65536,
        2097152, 32, 8192, 1024, 0, nullptr, nullptr, nullptr, nullptr);
    mgemm_kernel<EPI_NONE><<<dim3(64, 2, 8), blk, 0, stream>>>(
        W0, chan_v, OUT, 256, 2097152, 65536,
        2097152, 32, 8192, 1024, 0, nullptr, nullptr, nullptr, nullptr);

    // 7) fused channel attention + PV: msum(W2) += m_c
    chan_fused_kernel<<<2048, blk, 0, stream>>>(W1, OUT, W0, W2);

    // 8) topic relu GEMMs, split in batch halves: qg_lo->W1, qg_hi->OUT
    mgemm_kernel<EPI_RELU><<<dim3(64, 4, 4), blk, 0, stream>>>(
        W0, topic, W1, 256, 2097152, 131072,
        4194304, 131072, 512, 32, 0, nullptr, nullptr, nullptr, nullptr);
    mgemm_kernel<EPI_RELU><<<dim3(64, 4, 4), blk, 0, stream>>>(
        W0 + 4 * 2097152, topic + 4 * 131072, OUT, 256, 2097152, 131072,
        4194304, 131072, 512, 32, 0, nullptr, nullptr, nullptr, nullptr);

    // 9) rowsums -> W0[0:64K] (qzn dead); topicT[b][d][g] -> W0+65536
    rowsum_kernel<<<32768, blk, 0, stream>>>(W1, W0);
    rowsum_kernel<<<32768, blk, 0, stream>>>(OUT, W0 + 32768);
    tpose_kernel<<<dim3(16, 8, 8), blk, 0, stream>>>(topic, W0 + 65536, 512, 256);

    // 10) msum += (qg / rowsum) @ topic  (B = topicT, K=512)
    mgemm_kernel<EPI_TOPIC><<<dim3(64, 2, 4), blk, 0, stream>>>(
        W1, W0 + 65536, W2, 512, 4194304, 131072,
        2097152, 65536, 256, 32, 8192, nullptr, W0, nullptr, W2);
    mgemm_kernel<EPI_TOPIC><<<dim3(64, 2, 4), blk, 0, stream>>>(
        OUT, W0 + 65536 + 4 * 131072, W2 + 4 * 2097152, 512, 4194304, 131072,
        2097152, 65536, 256, 32, 8192, nullptr, W0 + 32768, nullptr, W2 + 4 * 2097152);

    // 11) gate + residual combine: qz2 -> W2 (in place over msum)
    mgemm_kernel<EPI_GATE><<<dim3(512, 2, 1), blk, 0, stream>>>(
        qz, gate_w, W2, 256, 0, 0,
        0, 65536, 256, 32, 0, gate_b, qz, unary, W2);

    // 12) output MLP with shared LN: h0=W0, h1=W1, final -> OUT
    ln_kernel<<<65536, blk, 0, stream>>>(W2, nsc, nbi, W0);
    mgemm_kernel<EPI_GELU><<<dim3(512, 2, 1), blk, 0, stream>>>(
        W0, w1, W1, 256, 0, 0,
        0, 65536, 256, 32, 0, b1, nullptr, nullptr, nullptr);
    mgemm_kernel<EPI_ADDRES><<<dim3(512, 2, 1), blk, 0, stream>>>(
        W1, w2, OUT, 256, 0, 0,
        0, 65536, 256, 32, 0, b2, W2, nullptr, nullptr);
}

// Round 5
// 884.098 us; speedup vs baseline: 2.3366x; 1.2704x over previous
//
#include <hip/hip_runtime.h>
#include <math.h>

namespace {

constexpr size_t ND = 16777216;   // B*C*P*D = 8*32*256*256
constexpr float INV_SQRT_R = 0.17677669529663689f;

typedef __attribute__((ext_vector_type(8))) __bf16 bf16x8;
typedef __attribute__((ext_vector_type(4))) float f32x4;

enum { EPI_NONE = 0, EPI_RELU, EPI_GATE, EPI_GELU, EPI_ADDRES, EPI_TOPIC };

// ---------------- LayerNorm over last dim (256) ----------------
__global__ __launch_bounds__(256) void ln_kernel(
    const float* __restrict__ x, const float* __restrict__ sc,
    const float* __restrict__ bi, float* __restrict__ y)
{
    const size_t row = blockIdx.x;
    const int t = threadIdx.x;
    const float v = x[row * 256 + t];
    float s = v, s2 = v * v;
    #pragma unroll
    for (int o = 32; o > 0; o >>= 1) {
        s  += __shfl_xor(s, o);
        s2 += __shfl_xor(s2, o);
    }
    __shared__ float ps[4], ps2[4];
    if ((t & 63) == 0) { ps[t >> 6] = s; ps2[t >> 6] = s2; }
    __syncthreads();
    const float S  = ps[0] + ps[1] + ps[2] + ps[3];
    const float S2 = ps2[0] + ps2[1] + ps2[2] + ps2[3];
    const float mean = S * (1.0f / 256.0f);
    const float var  = S2 * (1.0f / 256.0f) - mean * mean;
    const float inv  = 1.0f / sqrtf(var + 1e-5f);
    y[row * 256 + t] = (v - mean) * inv * sc[t] + bi[t];
}

// ---------------- Batched fp32 transpose: dst[c][r] = src[r][c] ----------------
__global__ __launch_bounds__(256) void tpose_kernel(
    const float* __restrict__ src, float* __restrict__ dst, int R, int C)
{
    const size_t bz = blockIdx.z;
    src += bz * (size_t)R * C;
    dst += bz * (size_t)R * C;
    __shared__ float tile[32][33];
    const int r0 = blockIdx.x * 32, c0 = blockIdx.y * 32;
    const int tx = threadIdx.x & 31, ty = threadIdx.x >> 5;
    #pragma unroll
    for (int i = 0; i < 32; i += 8)
        tile[ty + i][tx] = src[(size_t)(r0 + ty + i) * C + c0 + tx];
    __syncthreads();
    #pragma unroll
    for (int i = 0; i < 32; i += 8)
        dst[(size_t)(c0 + ty + i) * R + r0 + tx] = tile[tx][ty + i];
}

// ---------------- MFMA bf16 GEMM: C[m,n] = sum_k A[m,k]*B[n,k], ld = K ----------------
// 128x128 tile, BK=32, 4 waves (2x2), per-wave 64x64 (4x4 frags of 16x16x32).
// Output offset = bb*s_b + (m>>8)*s_c + (m&255)*s_p + (n>>5)*s_h + (n&31)
template<int EPI>
__global__ __launch_bounds__(256) void mgemm_kernel(
    const float* __restrict__ A, const float* __restrict__ Bm, float* __restrict__ Cout,
    int K, size_t aStride, size_t bStride,
    size_t s_b, size_t s_c, size_t s_p, size_t s_h, int Mrows,
    const float* __restrict__ bias, const float* __restrict__ e0,
    const float* __restrict__ e1, const float* __restrict__ e2)
{
    const int bb = blockIdx.z;
    const int m0 = blockIdx.x * 128;
    const int n0 = blockIdx.y * 128;
    const float* Ab = A + (size_t)bb * aStride;
    const float* Bb = Bm + (size_t)bb * bStride;
    __shared__ __align__(16) __bf16 As[128][40];   // pad 40: conflict-free b128 reads
    __shared__ __align__(16) __bf16 Bs[128][40];
    const int t = threadIdx.x;
    const int lane = t & 63;
    const int wid = t >> 6;
    const int wr = wid >> 1, wc = wid & 1;
    const int l15 = lane & 15, lg = lane >> 4;

    f32x4 acc[4][4] = {};

    for (int k0 = 0; k0 < K; k0 += 32) {
        #pragma unroll
        for (int i = 0; i < 2; ++i) {
            const int slot = i * 256 + t;          // 0..511
            const int row = slot >> 2;
            const int k8 = (slot & 3) << 3;
            {
                const float* src = Ab + (size_t)(m0 + row) * K + k0 + k8;
                float4 v0 = *(const float4*)src;
                float4 v1 = *(const float4*)(src + 4);
                bf16x8 pk;
                pk[0] = (__bf16)v0.x; pk[1] = (__bf16)v0.y; pk[2] = (__bf16)v0.z; pk[3] = (__bf16)v0.w;
                pk[4] = (__bf16)v1.x; pk[5] = (__bf16)v1.y; pk[6] = (__bf16)v1.z; pk[7] = (__bf16)v1.w;
                *(bf16x8*)&As[row][k8] = pk;
            }
            {
                const float* src = Bb + (size_t)(n0 + row) * K + k0 + k8;
                float4 v0 = *(const float4*)src;
                float4 v1 = *(const float4*)(src + 4);
                bf16x8 pk;
                pk[0] = (__bf16)v0.x; pk[1] = (__bf16)v0.y; pk[2] = (__bf16)v0.z; pk[3] = (__bf16)v0.w;
                pk[4] = (__bf16)v1.x; pk[5] = (__bf16)v1.y; pk[6] = (__bf16)v1.z; pk[7] = (__bf16)v1.w;
                *(bf16x8*)&Bs[row][k8] = pk;
            }
        }
        __syncthreads();
        bf16x8 af[4], bfr[4];
        #pragma unroll
        for (int i = 0; i < 4; ++i)
            af[i] = *(const bf16x8*)&As[wr * 64 + i * 16 + l15][lg * 8];
        #pragma unroll
        for (int j = 0; j < 4; ++j)
            bfr[j] = *(const bf16x8*)&Bs[wc * 64 + j * 16 + l15][lg * 8];
        #pragma unroll
        for (int i = 0; i < 4; ++i)
            #pragma unroll
            for (int j = 0; j < 4; ++j)
                acc[i][j] = __builtin_amdgcn_mfma_f32_16x16x32_bf16(af[i], bfr[j], acc[i][j], 0, 0, 0);
        __syncthreads();
    }

    // Epilogue: lane's element (i,j,r): m = m0+wr*64+i*16+lg*4+r, n = n0+wc*64+j*16+l15
    #pragma unroll
    for (int j = 0; j < 4; ++j) {
        const int n = n0 + wc * 64 + j * 16 + l15;
        const size_t offn = (size_t)(n >> 5) * s_h + (n & 31);
        float bn = 0.0f;
        if (EPI == EPI_GELU || EPI == EPI_GATE || EPI == EPI_ADDRES) bn = bias[n];
        #pragma unroll
        for (int i = 0; i < 4; ++i) {
            #pragma unroll
            for (int r = 0; r < 4; ++r) {
                const int m = m0 + wr * 64 + i * 16 + lg * 4 + r;
                const size_t off = (size_t)bb * s_b + (size_t)(m >> 8) * s_c
                                 + (size_t)(m & 255) * s_p + offn;
                float v = acc[i][j][r];
                if (EPI == EPI_RELU) {
                    v = fmaxf(v, 0.0f);
                } else if (EPI == EPI_GELU) {
                    float x = v + bn;
                    v = 0.5f * x * (1.0f + erff(x * 0.7071067811865475f));
                } else if (EPI == EPI_GATE) {
                    float g = 1.0f / (1.0f + __expf(-(v + bn)));
                    v = g * e0[off] + (1.0f - g) * (e1[off] + e2[off]);
                } else if (EPI == EPI_ADDRES) {
                    v += bn + e0[off];
                } else if (EPI == EPI_TOPIC) {
                    float inv = 1.0f / fmaxf(e0[(size_t)bb * Mrows + m], 1e-6f);
                    v = e2[off] + v * inv;
                }
                Cout[off] = v;
            }
        }
    }
}

// ---------------- MFMA time attention: block = (bc, 64-row p-tile) ----------------
// qu/qv layout [bc][h][p][r] (fp32); writes head-averaged softmax Abar [bc][p][q] (fp32).
// 4 waves; wave w owns rows p0 + w*16 .. +15 (one 16-row strip x all 256 cols).
__global__ __launch_bounds__(256) void time_attn_mfma_kernel(
    const float* __restrict__ qu, const float* __restrict__ qv, float* __restrict__ abar)
{
    const int bc = blockIdx.x;
    const int p0 = blockIdx.y * 64;
    const float* quB = qu + (size_t)bc * 65536;
    const float* qvB = qv + (size_t)bc * 65536;
    __shared__ __align__(16) __bf16 Us[64][40];    // qu tile (this block's 64 rows)
    __shared__ __align__(16) __bf16 Vs[256][40];   // qv (all 256 rows)
    const int t = threadIdx.x;
    const int lane = t & 63;
    const int wid = t >> 6;
    const int l15 = lane & 15, lg = lane >> 4;

    f32x4 acc[16] = {};       // head-averaged probs: cols j*16+l15, rows wid*16+lg*4+r

    for (int h = 0; h < 8; ++h) {
        const float* quH = quB + h * 8192;
        const float* qvH = qvB + h * 8192;
        __syncthreads();      // previous iteration's reads done before overwrite
        {   // stage qu tile: 64 rows x 32 -> 256 slots
            const int row = t >> 2, k8 = (t & 3) << 3;
            const float* src = quH + (size_t)(p0 + row) * 32 + k8;
            float4 v0 = *(const float4*)src;
            float4 v1 = *(const float4*)(src + 4);
            bf16x8 pk;
            pk[0] = (__bf16)v0.x; pk[1] = (__bf16)v0.y; pk[2] = (__bf16)v0.z; pk[3] = (__bf16)v0.w;
            pk[4] = (__bf16)v1.x; pk[5] = (__bf16)v1.y; pk[6] = (__bf16)v1.z; pk[7] = (__bf16)v1.w;
            *(bf16x8*)&Us[row][k8] = pk;
        }
        #pragma unroll
        for (int i = 0; i < 4; ++i) {   // stage qv: 256 rows x 32 -> 1024 slots
            const int slot = i * 256 + t;
            const int row = slot >> 2, k8 = (slot & 3) << 3;
            const float* src = qvH + (size_t)row * 32 + k8;
            float4 v0 = *(const float4*)src;
            float4 v1 = *(const float4*)(src + 4);
            bf16x8 pk;
            pk[0] = (__bf16)v0.x; pk[1] = (__bf16)v0.y; pk[2] = (__bf16)v0.z; pk[3] = (__bf16)v0.w;
            pk[4] = (__bf16)v1.x; pk[5] = (__bf16)v1.y; pk[6] = (__bf16)v1.z; pk[7] = (__bf16)v1.w;
            *(bf16x8*)&Vs[row][k8] = pk;
        }
        __syncthreads();

        // S strip: 16 rows x 256 cols = 16 MFMAs (K=32 in one step)
        f32x4 s[16];
        bf16x8 a = *(const bf16x8*)&Us[wid * 16 + l15][lg * 8];
        #pragma unroll
        for (int j = 0; j < 16; ++j) {
            bf16x8 bfr = *(const bf16x8*)&Vs[j * 16 + l15][lg * 8];
            s[j] = __builtin_amdgcn_mfma_f32_16x16x32_bf16(a, bfr, (f32x4){0.f, 0.f, 0.f, 0.f}, 0, 0, 0);
        }

        // Row softmax (no max-sub: logits ~N(0,1), exp safe in fp32) + head-average accum
        #pragma unroll
        for (int r = 0; r < 4; ++r) {
            float e[16];
            float sum = 0.0f;
            #pragma unroll
            for (int j = 0; j < 16; ++j) {
                e[j] = __expf(s[j][r] * INV_SQRT_R);
                sum += e[j];
            }
            sum += __shfl_xor(sum, 1);
            sum += __shfl_xor(sum, 2);
            sum += __shfl_xor(sum, 4);
            sum += __shfl_xor(sum, 8);
            const float inv = 0.125f / sum;
            #pragma unroll
            for (int j = 0; j < 16; ++j) acc[j][r] += e[j] * inv;
        }
    }

    // Write Abar rows p0 + wid*16 + lg*4 + r, cols j*16 + l15
    float* dst = abar + (size_t)bc * 65536 + (size_t)(p0 + wid * 16 + lg * 4) * 256 + l15;
    #pragma unroll
    for (int r = 0; r < 4; ++r)
        #pragma unroll
        for (int j = 0; j < 16; ++j)
            dst[(size_t)r * 256 + j * 16] = acc[j][r];
}

// ---------------- Fused channel attention + PV: one block per (b,p) ----------------
__global__ __launch_bounds__(256) void chan_fused_kernel(
    const float* __restrict__ quc, const float* __restrict__ qvc,
    const float* __restrict__ qzn, float* msum)
{
    const int bp = blockIdx.x;
    const int b = bp >> 8, p = bp & 255;
    const float* quB = quc + (size_t)bp * 8192;
    const float* qvB = qvc + (size_t)bp * 8192;
    __shared__ float U[16896];          // qus[8448] + qvs[8448]; later bt[32*256]
    __shared__ float ab[32 * 33];
    float* qus = U;
    float* qvs = U + 8448;
    const int t = threadIdx.x;
    #pragma unroll
    for (int i = 0; i < 8; ++i) {
        int fi = i * 256 + t;
        float4 a = ((const float4*)quB)[fi];
        float4 bv = ((const float4*)qvB)[fi];
        int e = fi << 2;
        int base = ((e >> 10) * 32 + ((e >> 5) & 31)) * 33 + (e & 31);
        qus[base + 0] = a.x; qus[base + 1] = a.y; qus[base + 2] = a.z; qus[base + 3] = a.w;
        qvs[base + 0] = bv.x; qvs[base + 1] = bv.y; qvs[base + 2] = bv.z; qvs[base + 3] = bv.w;
    }
    __syncthreads();
    const int c = t >> 3, j = t & 7;    // 8-lane group per row c
    float acc[4] = {0.f, 0.f, 0.f, 0.f};
    for (int h = 0; h < 8; ++h) {
        float qur[32];
        #pragma unroll
        for (int r = 0; r < 32; ++r) qur[r] = qus[(h * 32 + c) * 33 + r];
        float s[4];
        #pragma unroll
        for (int jj = 0; jj < 4; ++jj) {
            int f = j * 4 + jj;
            const float* qvR = &qvs[(h * 32 + f) * 33];
            float a = 0.f;
            #pragma unroll
            for (int r = 0; r < 32; ++r) a += qur[r] * qvR[r];
            s[jj] = a * INV_SQRT_R;
        }
        float mx = fmaxf(fmaxf(s[0], s[1]), fmaxf(s[2], s[3]));
        mx = fmaxf(mx, __shfl_xor(mx, 1));
        mx = fmaxf(mx, __shfl_xor(mx, 2));
        mx = fmaxf(mx, __shfl_xor(mx, 4));
        float e0x = __expf(s[0] - mx), e1x = __expf(s[1] - mx);
        float e2x = __expf(s[2] - mx), e3x = __expf(s[3] - mx);
        float sum = e0x + e1x + e2x + e3x;
        sum += __shfl_xor(sum, 1);
        sum += __shfl_xor(sum, 2);
        sum += __shfl_xor(sum, 4);
        float inv = 0.125f / sum;
        acc[0] += e0x * inv; acc[1] += e1x * inv; acc[2] += e2x * inv; acc[3] += e3x * inv;
    }
    #pragma unroll
    for (int jj = 0; jj < 4; ++jj) ab[c * 33 + j * 4 + jj] = acc[jj];
    __syncthreads();                    // all attn reads of U done; ab complete
    float* bt = U;                      // reuse U for qzn rows [f][d]
    #pragma unroll 4
    for (int f = 0; f < 32; ++f)
        bt[f * 256 + t] = qzn[((size_t)(b * 32 + f) * 256 + p) * 256 + t];
    __syncthreads();
    for (int c2 = 0; c2 < 32; c2 += 2) {
        float a0 = 0.f, a1 = 0.f;
        #pragma unroll
        for (int f = 0; f < 32; ++f) {
            float v = bt[f * 256 + t];
            a0 += ab[c2 * 33 + f] * v;
            a1 += ab[(c2 + 1) * 33 + f] * v;
        }
        size_t off = ((size_t)(b * 32 + c2) * 256 + p) * 256 + t;
        msum[off] += a0;
        msum[off + 65536] += a1;
    }
}

// ---------------- Row L1 sums of qg [rows][512] ----------------
__global__ __launch_bounds__(256) void rowsum_kernel(
    const float* __restrict__ qg, float* __restrict__ rs)
{
    const size_t row = blockIdx.x;
    const int t = threadIdx.x;
    float v = qg[row * 512 + t] + qg[row * 512 + 256 + t];
    #pragma unroll
    for (int o = 32; o > 0; o >>= 1) v += __shfl_xor(v, o);
    __shared__ float ps[4];
    if ((t & 63) == 0) ps[t >> 6] = v;
    __syncthreads();
    if (t == 0) rs[row] = ps[0] + ps[1] + ps[2] + ps[3];
}

} // namespace

extern "C" void kernel_launch(void* const* d_in, const int* in_sizes, int n_in,
                              void* d_out, int out_size, void* d_ws, size_t ws_size,
                              hipStream_t stream)
{
    (void)in_sizes; (void)n_in; (void)out_size; (void)ws_size;
    const float* qz     = (const float*)d_in[0];
    const float* unary  = (const float*)d_in[1];
    const float* time_u = (const float*)d_in[2];
    const float* time_v = (const float*)d_in[3];
    const float* chan_u = (const float*)d_in[4];
    const float* chan_v = (const float*)d_in[5];
    const float* topic  = (const float*)d_in[6];
    const float* nsc    = (const float*)d_in[7];
    const float* nbi    = (const float*)d_in[8];
    const float* gate_w = (const float*)d_in[9];
    const float* gate_b = (const float*)d_in[10];
    const float* w1     = (const float*)d_in[11];
    const float* b1     = (const float*)d_in[12];
    const float* w2     = (const float*)d_in[13];
    const float* b2     = (const float*)d_in[14];

    // 3 x 64MB units in d_ws; d_out doubles as a 4th scratch unit.
    float* W0  = (float*)d_ws;            // qzn -> rowsums+topicT -> h0
    float* W1  = W0 + ND;                 // tu proj -> qznT -> cu proj -> qg_lo -> h1
    float* W2  = W0 + 2 * ND;             // tv proj -> msum -> qz2(in place)
    float* OUT = (float*)d_out;           // abar_t -> cv proj -> qg_hi -> final out

    dim3 blk(256);

    // 1) qz_n = LN(qz) -> W0
    ln_kernel<<<65536, blk, 0, stream>>>(qz, nsc, nbi, W0);

    // 2) time projections -> [b][c][h][p][r]
    mgemm_kernel<EPI_NONE><<<dim3(64, 2, 8), blk, 0, stream>>>(
        W0, time_u, W1, 256, 2097152, 65536,
        2097152, 65536, 32, 8192, 0, nullptr, nullptr, nullptr, nullptr);
    mgemm_kernel<EPI_NONE><<<dim3(64, 2, 8), blk, 0, stream>>>(
        W0, time_v, W2, 256, 2097152, 65536,
        2097152, 65536, 32, 8192, 0, nullptr, nullptr, nullptr, nullptr);

    // 3) head-averaged time attention (MFMA) -> Abar [bc][p][q] in OUT
    time_attn_mfma_kernel<<<dim3(256, 4), blk, 0, stream>>>(W1, W2, OUT);

    // 4) qznT[bc][d][p] -> W1 (tu proj dead). 256 batches of 256x256
    tpose_kernel<<<dim3(8, 8, 256), blk, 0, stream>>>(W0, W1, 256, 256);

    // 5) msum = m_t = Abar @ qzn -> W2 (tv proj dead); B = qznT per bc
    mgemm_kernel<EPI_NONE><<<dim3(2, 2, 256), blk, 0, stream>>>(
        OUT, W1, W2, 256, 65536, 65536,
        65536, 0, 256, 32, 0, nullptr, nullptr, nullptr, nullptr);

    // 6) channel projections -> [b][p][h][c][r]: cu -> W1, cv -> OUT
    mgemm_kernel<EPI_NONE><<<dim3(64, 2, 8), blk, 0, stream>>>(
        W0, chan_u, W1, 256, 2097152, 65536,
        2097152, 32, 8192, 1024, 0, nullptr, nullptr, nullptr, nullptr);
    mgemm_kernel<EPI_NONE><<<dim3(64, 2, 8), blk, 0, stream>>>(
        W0, chan_v, OUT, 256, 2097152, 65536,
        2097152, 32, 8192, 1024, 0, nullptr, nullptr, nullptr, nullptr);

    // 7) fused channel attention + PV: msum(W2) += m_c
    chan_fused_kernel<<<2048, blk, 0, stream>>>(W1, OUT, W0, W2);

    // 8) topic relu GEMMs, split in batch halves: qg_lo->W1, qg_hi->OUT
    mgemm_kernel<EPI_RELU><<<dim3(64, 4, 4), blk, 0, stream>>>(
        W0, topic, W1, 256, 2097152, 131072,
        4194304, 131072, 512, 32, 0, nullptr, nullptr, nullptr, nullptr);
    mgemm_kernel<EPI_RELU><<<dim3(64, 4, 4), blk, 0, stream>>>(
        W0 + 4 * 2097152, topic + 4 * 131072, OUT, 256, 2097152, 131072,
        4194304, 131072, 512, 32, 0, nullptr, nullptr, nullptr, nullptr);

    // 9) rowsums -> W0[0:64K] (qzn dead); topicT[b][d][g] -> W0+65536
    rowsum_kernel<<<32768, blk, 0, stream>>>(W1, W0);
    rowsum_kernel<<<32768, blk, 0, stream>>>(OUT, W0 + 32768);
    tpose_kernel<<<dim3(16, 8, 8), blk, 0, stream>>>(topic, W0 + 65536, 512, 256);

    // 10) msum += (qg / rowsum) @ topic  (B = topicT, K=512)
    mgemm_kernel<EPI_TOPIC><<<dim3(64, 2, 4), blk, 0, stream>>>(
        W1, W0 + 65536, W2, 512, 4194304, 131072,
        2097152, 65536, 256, 32, 8192, nullptr, W0, nullptr, W2);
    mgemm_kernel<EPI_TOPIC><<<dim3(64, 2, 4), blk, 0, stream>>>(
        OUT, W0 + 65536 + 4 * 131072, W2 + 4 * 2097152, 512, 4194304, 131072,
        2097152, 65536, 256, 32, 8192, nullptr, W0 + 32768, nullptr, W2 + 4 * 2097152);

    // 11) gate + residual combine: qz2 -> W2 (in place over msum)
    mgemm_kernel<EPI_GATE><<<dim3(512, 2, 1), blk, 0, stream>>>(
        qz, gate_w, W2, 256, 0, 0,
        0, 65536, 256, 32, 0, gate_b, qz, unary, W2);

    // 12) output MLP with shared LN: h0=W0, h1=W1, final -> OUT
    ln_kernel<<<65536, blk, 0, stream>>>(W2, nsc, nbi, W0);
    mgemm_kernel<EPI_GELU><<<dim3(512, 2, 1), blk, 0, stream>>>(
        W0, w1, W1, 256, 0, 0,
        0, 65536, 256, 32, 0, b1, nullptr, nullptr, nullptr);
    mgemm_kernel<EPI_ADDRES><<<dim3(512, 2, 1), blk, 0, stream>>>(
        W1, w2, OUT, 256, 0, 0,
        0, 65536, 256, 32, 0, b2, W2, nullptr, nullptr);
}

// Round 6
// 773.292 us; speedup vs baseline: 2.6714x; 1.1433x over previous
//
#include <hip/hip_runtime.h>
#include <math.h>

namespace {

constexpr float INV_SQRT_R = 0.17677669529663689f;

typedef __attribute__((ext_vector_type(8))) __bf16 bf16x8;
typedef __attribute__((ext_vector_type(4))) float f32x4;

enum { EPI_NONE = 0, EPI_RELU, EPI_GATE, EPI_GELU, EPI_ADDRES, EPI_TOPIC };

// ---------------- fp32 -> bf16 elementwise ----------------
__global__ __launch_bounds__(256) void cvt_kernel(
    const float* __restrict__ src, __bf16* __restrict__ dst, int n)
{
    int i = (blockIdx.x * 256 + threadIdx.x) * 4;
    if (i < n) {
        float4 v = *(const float4*)(src + i);
        dst[i + 0] = (__bf16)v.x; dst[i + 1] = (__bf16)v.y;
        dst[i + 2] = (__bf16)v.z; dst[i + 3] = (__bf16)v.w;
    }
}

// ---------------- LayerNorm over last dim (256), bf16 out ----------------
__global__ __launch_bounds__(256) void ln_kernel(
    const float* __restrict__ x, const float* __restrict__ sc,
    const float* __restrict__ bi, __bf16* __restrict__ y)
{
    const size_t row = blockIdx.x;
    const int t = threadIdx.x;
    const float v = x[row * 256 + t];
    float s = v, s2 = v * v;
    #pragma unroll
    for (int o = 32; o > 0; o >>= 1) {
        s  += __shfl_xor(s, o);
        s2 += __shfl_xor(s2, o);
    }
    __shared__ float ps[4], ps2[4];
    if ((t & 63) == 0) { ps[t >> 6] = s; ps2[t >> 6] = s2; }
    __syncthreads();
    const float S  = ps[0] + ps[1] + ps[2] + ps[3];
    const float S2 = ps2[0] + ps2[1] + ps2[2] + ps2[3];
    const float mean = S * (1.0f / 256.0f);
    const float var  = S2 * (1.0f / 256.0f) - mean * mean;
    const float inv  = 1.0f / sqrtf(var + 1e-5f);
    y[row * 256 + t] = (__bf16)((v - mean) * inv * sc[t] + bi[t]);
}

// ---------------- Batched bf16 transpose: dst[c][r] = src[r][c] ----------------
__global__ __launch_bounds__(256) void tpose_bf_kernel(
    const __bf16* __restrict__ src, __bf16* __restrict__ dst, int R, int C)
{
    const size_t bz = blockIdx.z;
    src += bz * (size_t)R * C;
    dst += bz * (size_t)R * C;
    __shared__ __bf16 tile[32][34];
    const int r0 = blockIdx.x * 32, c0 = blockIdx.y * 32;
    const int tx = threadIdx.x & 31, ty = threadIdx.x >> 5;
    #pragma unroll
    for (int i = 0; i < 32; i += 8)
        tile[ty + i][tx] = src[(size_t)(r0 + ty + i) * C + c0 + tx];
    __syncthreads();
    #pragma unroll
    for (int i = 0; i < 32; i += 8)
        dst[(size_t)(c0 + ty + i) * R + r0 + tx] = tile[tx][ty + i];
}

// ---------------- Batched cvt-transpose fp32->bf16 ----------------
__global__ __launch_bounds__(256) void tpose_cvt_kernel(
    const float* __restrict__ src, __bf16* __restrict__ dst, int R, int C)
{
    const size_t bz = blockIdx.z;
    src += bz * (size_t)R * C;
    dst += bz * (size_t)R * C;
    __shared__ __bf16 tile[32][34];
    const int r0 = blockIdx.x * 32, c0 = blockIdx.y * 32;
    const int tx = threadIdx.x & 31, ty = threadIdx.x >> 5;
    #pragma unroll
    for (int i = 0; i < 32; i += 8)
        tile[ty + i][tx] = (__bf16)src[(size_t)(r0 + ty + i) * C + c0 + tx];
    __syncthreads();
    #pragma unroll
    for (int i = 0; i < 32; i += 8)
        dst[(size_t)(c0 + ty + i) * R + r0 + tx] = tile[tx][ty + i];
}

// ---------------- MFMA bf16 GEMM: C[m,n] = sum_k A[m,k]*B[n,k], ld = K ----------------
// A,B bf16. OBF: 1 -> bf16 output, 0 -> fp32 output.
// Output offset = bb*s_b + (m>>8)*s_c + (m&255)*s_p + (n>>5)*s_h + (n&31)
template<int EPI, int OBF>
__global__ __launch_bounds__(256) void mgemm_kernel(
    const __bf16* __restrict__ A, const __bf16* __restrict__ Bm, void* __restrict__ CoutV,
    int K, size_t aStride, size_t bStride,
    size_t s_b, size_t s_c, size_t s_p, size_t s_h, int Mrows,
    const float* __restrict__ bias, const float* __restrict__ e0,
    const float* __restrict__ e1, const float* __restrict__ e2)
{
    const int bb = blockIdx.z;
    const int m0 = blockIdx.x * 128;
    const int n0 = blockIdx.y * 128;
    const __bf16* Ab = A + (size_t)bb * aStride;
    const __bf16* Bb = Bm + (size_t)bb * bStride;
    __shared__ __align__(16) __bf16 As[128][40];   // pad 40: conflict-free b128 reads
    __shared__ __align__(16) __bf16 Bs[128][40];
    const int t = threadIdx.x;
    const int lane = t & 63;
    const int wid = t >> 6;
    const int wr = wid >> 1, wc = wid & 1;
    const int l15 = lane & 15, lg = lane >> 4;

    f32x4 acc[4][4] = {};

    for (int k0 = 0; k0 < K; k0 += 32) {
        #pragma unroll
        for (int i = 0; i < 2; ++i) {
            const int slot = i * 256 + t;          // 0..511
            const int row = slot >> 2;
            const int k8 = (slot & 3) << 3;
            *(bf16x8*)&As[row][k8] = *(const bf16x8*)(Ab + (size_t)(m0 + row) * K + k0 + k8);
            *(bf16x8*)&Bs[row][k8] = *(const bf16x8*)(Bb + (size_t)(n0 + row) * K + k0 + k8);
        }
        __syncthreads();
        bf16x8 af[4], bfr[4];
        #pragma unroll
        for (int i = 0; i < 4; ++i)
            af[i] = *(const bf16x8*)&As[wr * 64 + i * 16 + l15][lg * 8];
        #pragma unroll
        for (int j = 0; j < 4; ++j)
            bfr[j] = *(const bf16x8*)&Bs[wc * 64 + j * 16 + l15][lg * 8];
        #pragma unroll
        for (int i = 0; i < 4; ++i)
            #pragma unroll
            for (int j = 0; j < 4; ++j)
                acc[i][j] = __builtin_amdgcn_mfma_f32_16x16x32_bf16(af[i], bfr[j], acc[i][j], 0, 0, 0);
        __syncthreads();
    }

    // Epilogue: lane's element (i,j,r): m = m0+wr*64+i*16+lg*4+r, n = n0+wc*64+j*16+l15
    #pragma unroll
    for (int j = 0; j < 4; ++j) {
        const int n = n0 + wc * 64 + j * 16 + l15;
        const size_t offn = (size_t)(n >> 5) * s_h + (n & 31);
        float bn = 0.0f;
        if (EPI == EPI_GELU || EPI == EPI_GATE || EPI == EPI_ADDRES) bn = bias[n];
        #pragma unroll
        for (int i = 0; i < 4; ++i) {
            #pragma unroll
            for (int r = 0; r < 4; ++r) {
                const int m = m0 + wr * 64 + i * 16 + lg * 4 + r;
                const size_t off = (size_t)bb * s_b + (size_t)(m >> 8) * s_c
                                 + (size_t)(m & 255) * s_p + offn;
                float v = acc[i][j][r];
                if (EPI == EPI_RELU) {
                    v = fmaxf(v, 0.0f);
                } else if (EPI == EPI_GELU) {
                    float x = v + bn;
                    v = 0.5f * x * (1.0f + erff(x * 0.7071067811865475f));
                } else if (EPI == EPI_GATE) {
                    float g = 1.0f / (1.0f + __expf(-(v + bn)));
                    v = g * e0[off] + (1.0f - g) * (e1[off] + e2[off]);
                } else if (EPI == EPI_ADDRES) {
                    v += bn + e0[off];
                } else if (EPI == EPI_TOPIC) {
                    float inv = 1.0f / fmaxf(e0[(size_t)bb * Mrows + m], 1e-6f);
                    v = e2[off] + v * inv;
                }
                if (OBF) ((__bf16*)CoutV)[off] = (__bf16)v;
                else     ((float*)CoutV)[off] = v;
            }
        }
    }
}

// ---------------- MFMA time attention: block = (bc, 64-row p-tile) ----------------
// qu/qv layout [bc][h][p][r] (bf16); writes head-averaged softmax Abar [bc][p][q] (bf16).
__global__ __launch_bounds__(256) void time_attn_mfma_kernel(
    const __bf16* __restrict__ qu, const __bf16* __restrict__ qv, __bf16* __restrict__ abar)
{
    const int bc = blockIdx.x;
    const int p0 = blockIdx.y * 64;
    const __bf16* quB = qu + (size_t)bc * 65536;
    const __bf16* qvB = qv + (size_t)bc * 65536;
    __shared__ __align__(16) __bf16 Us[64][40];    // qu tile (this block's 64 rows)
    __shared__ __align__(16) __bf16 Vs[256][40];   // qv (all 256 rows)
    const int t = threadIdx.x;
    const int lane = t & 63;
    const int wid = t >> 6;
    const int l15 = lane & 15, lg = lane >> 4;

    f32x4 acc[16] = {};       // head-averaged probs: cols j*16+l15, rows wid*16+lg*4+r

    for (int h = 0; h < 8; ++h) {
        const __bf16* quH = quB + h * 8192;
        const __bf16* qvH = qvB + h * 8192;
        __syncthreads();      // previous iteration's reads done before overwrite
        {   // stage qu tile: 64 rows x 4 slots of 8
            const int row = t >> 2, k8 = (t & 3) << 3;
            *(bf16x8*)&Us[row][k8] = *(const bf16x8*)(quH + (size_t)(p0 + row) * 32 + k8);
        }
        #pragma unroll
        for (int i = 0; i < 4; ++i) {   // stage qv: 256 rows x 4 slots
            const int slot = i * 256 + t;
            const int row = slot >> 2, k8 = (slot & 3) << 3;
            *(bf16x8*)&Vs[row][k8] = *(const bf16x8*)(qvH + (size_t)row * 32 + k8);
        }
        __syncthreads();

        // S strip: 16 rows x 256 cols = 16 MFMAs (K=32 in one step)
        f32x4 s[16];
        bf16x8 a = *(const bf16x8*)&Us[wid * 16 + l15][lg * 8];
        #pragma unroll
        for (int j = 0; j < 16; ++j) {
            bf16x8 bfr = *(const bf16x8*)&Vs[j * 16 + l15][lg * 8];
            s[j] = __builtin_amdgcn_mfma_f32_16x16x32_bf16(a, bfr, (f32x4){0.f, 0.f, 0.f, 0.f}, 0, 0, 0);
        }

        // Row softmax (no max-sub: logits ~N(0,1), exp safe) + head-average accum
        #pragma unroll
        for (int r = 0; r < 4; ++r) {
            float e[16];
            float sum = 0.0f;
            #pragma unroll
            for (int j = 0; j < 16; ++j) {
                e[j] = __expf(s[j][r] * INV_SQRT_R);
                sum += e[j];
            }
            sum += __shfl_xor(sum, 1);
            sum += __shfl_xor(sum, 2);
            sum += __shfl_xor(sum, 4);
            sum += __shfl_xor(sum, 8);
            const float inv = 0.125f / sum;
            #pragma unroll
            for (int j = 0; j < 16; ++j) acc[j][r] += e[j] * inv;
        }
    }

    __bf16* dst = abar + (size_t)bc * 65536 + (size_t)(p0 + wid * 16 + lg * 4) * 256 + l15;
    #pragma unroll
    for (int r = 0; r < 4; ++r)
        #pragma unroll
        for (int j = 0; j < 16; ++j)
            dst[(size_t)r * 256 + j * 16] = (__bf16)acc[j][r];
}

// ---------------- Fused channel attention + PV: one block per (b,p) ----------------
// quc/qvc bf16 [b][p][h][c][r]; qzn bf16; msum fp32 RMW.
__global__ __launch_bounds__(256) void chan_fused_kernel(
    const __bf16* __restrict__ quc, const __bf16* __restrict__ qvc,
    const __bf16* __restrict__ qzn, float* msum)
{
    const int bp = blockIdx.x;
    const int b = bp >> 8, p = bp & 255;
    const __bf16* quB = quc + (size_t)bp * 8192;
    const __bf16* qvB = qvc + (size_t)bp * 8192;
    __shared__ float U[16896];          // qus[8448] + qvs[8448]; later bt[32*256]
    __shared__ float ab[32 * 33];
    float* qus = U;
    float* qvs = U + 8448;
    const int t = threadIdx.x;
    #pragma unroll
    for (int i = 0; i < 4; ++i) {
        int fi = i * 256 + t;           // 0..1023 chunks of 8
        int e = fi << 3;
        bf16x8 a = *(const bf16x8*)(quB + e);
        bf16x8 bv = *(const bf16x8*)(qvB + e);
        int base = ((e >> 10) * 32 + ((e >> 5) & 31)) * 33 + (e & 31);
        #pragma unroll
        for (int j = 0; j < 8; ++j) {
            qus[base + j] = (float)a[j];
            qvs[base + j] = (float)bv[j];
        }
    }
    __syncthreads();
    const int c = t >> 3, j = t & 7;    // 8-lane group per row c
    float acc[4] = {0.f, 0.f, 0.f, 0.f};
    for (int h = 0; h < 8; ++h) {
        float qur[32];
        #pragma unroll
        for (int r = 0; r < 32; ++r) qur[r] = qus[(h * 32 + c) * 33 + r];
        float s[4];
        #pragma unroll
        for (int jj = 0; jj < 4; ++jj) {
            int f = j * 4 + jj;
            const float* qvR = &qvs[(h * 32 + f) * 33];
            float a = 0.f;
            #pragma unroll
            for (int r = 0; r < 32; ++r) a += qur[r] * qvR[r];
            s[jj] = a * INV_SQRT_R;
        }
        float mx = fmaxf(fmaxf(s[0], s[1]), fmaxf(s[2], s[3]));
        mx = fmaxf(mx, __shfl_xor(mx, 1));
        mx = fmaxf(mx, __shfl_xor(mx, 2));
        mx = fmaxf(mx, __shfl_xor(mx, 4));
        float e0x = __expf(s[0] - mx), e1x = __expf(s[1] - mx);
        float e2x = __expf(s[2] - mx), e3x = __expf(s[3] - mx);
        float sum = e0x + e1x + e2x + e3x;
        sum += __shfl_xor(sum, 1);
        sum += __shfl_xor(sum, 2);
        sum += __shfl_xor(sum, 4);
        float inv = 0.125f / sum;
        acc[0] += e0x * inv; acc[1] += e1x * inv; acc[2] += e2x * inv; acc[3] += e3x * inv;
    }
    #pragma unroll
    for (int jj = 0; jj < 4; ++jj) ab[c * 33 + j * 4 + jj] = acc[jj];
    __syncthreads();                    // all attn reads of U done; ab complete
    float* bt = U;                      // reuse U for qzn rows [f][d]
    #pragma unroll 4
    for (int f = 0; f < 32; ++f)
        bt[f * 256 + t] = (float)qzn[((size_t)(b * 32 + f) * 256 + p) * 256 + t];
    __syncthreads();
    for (int c2 = 0; c2 < 32; c2 += 2) {
        float a0 = 0.f, a1 = 0.f;
        #pragma unroll
        for (int f = 0; f < 32; ++f) {
            float v = bt[f * 256 + t];
            a0 += ab[c2 * 33 + f] * v;
            a1 += ab[(c2 + 1) * 33 + f] * v;
        }
        size_t off = ((size_t)(b * 32 + c2) * 256 + p) * 256 + t;
        msum[off] += a0;
        msum[off + 65536] += a1;
    }
}

// ---------------- Row L1 sums of qg (bf16) [rows][512] ----------------
__global__ __launch_bounds__(256) void rowsum_kernel(
    const __bf16* __restrict__ qg, float* __restrict__ rs)
{
    const size_t row = blockIdx.x;
    const int t = threadIdx.x;
    float v = (float)qg[row * 512 + t] + (float)qg[row * 512 + 256 + t];
    #pragma unroll
    for (int o = 32; o > 0; o >>= 1) v += __shfl_xor(v, o);
    __shared__ float ps[4];
    if ((t & 63) == 0) ps[t >> 6] = v;
    __syncthreads();
    if (t == 0) rs[row] = ps[0] + ps[1] + ps[2] + ps[3];
}

} // namespace

extern "C" void kernel_launch(void* const* d_in, const int* in_sizes, int n_in,
                              void* d_out, int out_size, void* d_ws, size_t ws_size,
                              hipStream_t stream)
{
    (void)in_sizes; (void)n_in; (void)out_size; (void)ws_size;
    const float* qz     = (const float*)d_in[0];
    const float* unary  = (const float*)d_in[1];
    const float* time_u = (const float*)d_in[2];
    const float* time_v = (const float*)d_in[3];
    const float* chan_u = (const float*)d_in[4];
    const float* chan_v = (const float*)d_in[5];
    const float* topic  = (const float*)d_in[6];
    const float* nsc    = (const float*)d_in[7];
    const float* nbi    = (const float*)d_in[8];
    const float* gate_w = (const float*)d_in[9];
    const float* gate_b = (const float*)d_in[10];
    const float* w1     = (const float*)d_in[11];
    const float* b1     = (const float*)d_in[12];
    const float* w2     = (const float*)d_in[13];
    const float* b2     = (const float*)d_in[14];

    // Workspace map (192 MB in d_ws + 64 MB d_out):
    //  [0,32MB)   A.lo: qzn_b -> rowsums -> h0_b
    //  [32,64MB)  A.hi: bf16 weight pool (whole run)
    //  [64,128MB) B:    qu_t|qv_t -> qznT -> qu_c|qv_c -> qg_lo -> qz_b|h1_b
    //  [128,192MB)C:    msum (fp32) -> qz2 (in place)
    //  d_out  D:        abar -> qg_hi -> final out
    char* base = (char*)d_ws;
    __bf16* qzn_b = (__bf16*)base;
    float*  rs    = (float*)base;                    // after qzn dead
    __bf16* h0b   = (__bf16*)base;
    __bf16* pool  = (__bf16*)(base + (32ull << 20));
    __bf16* wtu    = pool;
    __bf16* wtv    = pool + 524288;
    __bf16* wcu    = pool + 1048576;
    __bf16* wcv    = pool + 1572864;
    __bf16* topicb = pool + 2097152;
    __bf16* topicTb= pool + 3145728;
    __bf16* gwb    = pool + 4194304;
    __bf16* w1b    = pool + 4259840;
    __bf16* w2b    = pool + 4325376;
    __bf16* B16   = (__bf16*)(base + (64ull << 20));
    __bf16* qu_t  = B16;
    __bf16* qv_t  = B16 + 16777216;
    __bf16* qznT  = B16;
    __bf16* qu_c  = B16;
    __bf16* qv_c  = B16 + 16777216;
    __bf16* qg_lo = B16;
    __bf16* qzb   = B16;
    __bf16* h1b   = B16 + 16777216;
    float*  msum  = (float*)(base + (128ull << 20));
    float*  qz2   = msum;
    __bf16* abar  = (__bf16*)d_out;
    __bf16* qg_hi = (__bf16*)d_out;
    float*  OUTF  = (float*)d_out;

    dim3 blk(256);

    // 0) one-time weight conversions to bf16
    cvt_kernel<<<512, blk, 0, stream>>>(time_u, wtu, 524288);
    cvt_kernel<<<512, blk, 0, stream>>>(time_v, wtv, 524288);
    cvt_kernel<<<512, blk, 0, stream>>>(chan_u, wcu, 524288);
    cvt_kernel<<<512, blk, 0, stream>>>(chan_v, wcv, 524288);
    cvt_kernel<<<1024, blk, 0, stream>>>(topic, topicb, 1048576);
    cvt_kernel<<<64, blk, 0, stream>>>(gate_w, gwb, 65536);
    cvt_kernel<<<64, blk, 0, stream>>>(w1, w1b, 65536);
    cvt_kernel<<<64, blk, 0, stream>>>(w2, w2b, 65536);
    tpose_cvt_kernel<<<dim3(16, 8, 8), blk, 0, stream>>>(topic, topicTb, 512, 256);

    // 1) qz_n = LN(qz) -> qzn_b (bf16)
    ln_kernel<<<65536, blk, 0, stream>>>(qz, nsc, nbi, qzn_b);

    // 2) time projections -> [b][c][h][p][r] (bf16)
    mgemm_kernel<EPI_NONE, 1><<<dim3(64, 2, 8), blk, 0, stream>>>(
        qzn_b, wtu, qu_t, 256, 2097152, 65536,
        2097152, 65536, 32, 8192, 0, nullptr, nullptr, nullptr, nullptr);
    mgemm_kernel<EPI_NONE, 1><<<dim3(64, 2, 8), blk, 0, stream>>>(
        qzn_b, wtv, qv_t, 256, 2097152, 65536,
        2097152, 65536, 32, 8192, 0, nullptr, nullptr, nullptr, nullptr);

    // 3) head-averaged time attention (MFMA) -> abar (bf16, D)
    time_attn_mfma_kernel<<<dim3(256, 4), blk, 0, stream>>>(qu_t, qv_t, abar);

    // 4) qznT[bc][d][p] (bf16) -> B.lo (qu_t dead)
    tpose_bf_kernel<<<dim3(8, 8, 256), blk, 0, stream>>>(qzn_b, qznT, 256, 256);

    // 5) msum = m_t = abar @ qzn -> C (fp32)
    mgemm_kernel<EPI_NONE, 0><<<dim3(2, 2, 256), blk, 0, stream>>>(
        abar, qznT, msum, 256, 65536, 65536,
        65536, 0, 256, 32, 0, nullptr, nullptr, nullptr, nullptr);

    // 6) channel projections -> [b][p][h][c][r] (bf16): cu -> B.lo, cv -> B.hi
    mgemm_kernel<EPI_NONE, 1><<<dim3(64, 2, 8), blk, 0, stream>>>(
        qzn_b, wcu, qu_c, 256, 2097152, 65536,
        2097152, 32, 8192, 1024, 0, nullptr, nullptr, nullptr, nullptr);
    mgemm_kernel<EPI_NONE, 1><<<dim3(64, 2, 8), blk, 0, stream>>>(
        qzn_b, wcv, qv_c, 256, 2097152, 65536,
        2097152, 32, 8192, 1024, 0, nullptr, nullptr, nullptr, nullptr);

    // 7) fused channel attention + PV: msum += m_c
    chan_fused_kernel<<<2048, blk, 0, stream>>>(qu_c, qv_c, qzn_b, msum);

    // 8) topic relu GEMMs (bf16 out), batch halves: lo -> B, hi -> D (abar dead)
    mgemm_kernel<EPI_RELU, 1><<<dim3(64, 4, 4), blk, 0, stream>>>(
        qzn_b, topicb, qg_lo, 256, 2097152, 131072,
        4194304, 131072, 512, 32, 0, nullptr, nullptr, nullptr, nullptr);
    mgemm_kernel<EPI_RELU, 1><<<dim3(64, 4, 4), blk, 0, stream>>>(
        qzn_b + 4 * 2097152, topicb + 4 * 131072, qg_hi, 256, 2097152, 131072,
        4194304, 131072, 512, 32, 0, nullptr, nullptr, nullptr, nullptr);

    // 9) rowsums -> A.lo (qzn dead)
    rowsum_kernel<<<32768, blk, 0, stream>>>(qg_lo, rs);
    rowsum_kernel<<<32768, blk, 0, stream>>>(qg_hi, rs + 32768);

    // 10) msum += (qg / rowsum) @ topic  (B = topicT bf16, K=512)
    mgemm_kernel<EPI_TOPIC, 0><<<dim3(64, 2, 4), blk, 0, stream>>>(
        qg_lo, topicTb, msum, 512, 4194304, 131072,
        2097152, 65536, 256, 32, 8192, nullptr, rs, nullptr, msum);
    mgemm_kernel<EPI_TOPIC, 0><<<dim3(64, 2, 4), blk, 0, stream>>>(
        qg_hi, topicTb + 4 * 131072, msum + 4 * 2097152, 512, 4194304, 131072,
        2097152, 65536, 256, 32, 8192, nullptr, rs + 32768, nullptr, msum + 4 * 2097152);

    // 10.5) qz -> bf16 (B.lo, qg_lo dead)
    cvt_kernel<<<16384, blk, 0, stream>>>(qz, qzb, 16777216);

    // 11) gate + residual combine: qz2 (fp32) in place over msum
    mgemm_kernel<EPI_GATE, 0><<<dim3(512, 2, 1), blk, 0, stream>>>(
        qzb, gwb, qz2, 256, 0, 0,
        0, 65536, 256, 32, 0, gate_b, qz, unary, msum);

    // 12) output MLP: h0 = LN(qz2) bf16 -> A.lo; h1 bf16 -> B.hi; final fp32 -> D
    ln_kernel<<<65536, blk, 0, stream>>>(qz2, nsc, nbi, h0b);
    mgemm_kernel<EPI_GELU, 1><<<dim3(512, 2, 1), blk, 0, stream>>>(
        h0b, w1b, h1b, 256, 0, 0,
        0, 65536, 256, 32, 0, b1, nullptr, nullptr, nullptr);
    mgemm_kernel<EPI_ADDRES, 0><<<dim3(512, 2, 1), blk, 0, stream>>>(
        h1b, w2b, OUTF, 256, 0, 0,
        0, 65536, 256, 32, 0, b2, qz2, nullptr, nullptr);
}

// Round 7
// 682.141 us; speedup vs baseline: 3.0284x; 1.1336x over previous
//
#include <hip/hip_runtime.h>
#include <math.h>

namespace {

constexpr float INV_SQRT_R = 0.17677669529663689f;

typedef __attribute__((ext_vector_type(8))) __bf16 bf16x8;
typedef __attribute__((ext_vector_type(4))) float f32x4;

enum { EPI_NONE = 0, EPI_RELU, EPI_GATE, EPI_GELU, EPI_ADDRES, EPI_SCALE };

// ---------------- fp32 -> bf16 elementwise ----------------
__global__ __launch_bounds__(256) void cvt_kernel(
    const float* __restrict__ src, __bf16* __restrict__ dst, int n)
{
    int i = (blockIdx.x * 256 + threadIdx.x) * 4;
    if (i < n) {
        float4 v = *(const float4*)(src + i);
        dst[i + 0] = (__bf16)v.x; dst[i + 1] = (__bf16)v.y;
        dst[i + 2] = (__bf16)v.z; dst[i + 3] = (__bf16)v.w;
    }
}

// fp32 -> bf16 with 64K-chunk restride (for stacking per-batch weight pairs)
__global__ __launch_bounds__(256) void cvt2_kernel(
    const float* __restrict__ src, __bf16* __restrict__ dst, int n,
    int dstChunk, int dstOff)
{
    int i = (blockIdx.x * 256 + threadIdx.x) * 4;
    if (i < n) {
        float4 v = *(const float4*)(src + i);
        int o = (i >> 16) * dstChunk + dstOff + (i & 65535);
        dst[o + 0] = (__bf16)v.x; dst[o + 1] = (__bf16)v.y;
        dst[o + 2] = (__bf16)v.z; dst[o + 3] = (__bf16)v.w;
    }
}

__global__ __launch_bounds__(256) void zero_kernel(float* __restrict__ p, int n)
{
    int i = blockIdx.x * 256 + threadIdx.x;
    if (i < n) p[i] = 0.0f;
}

// ---------------- LayerNorm over last dim (256), bf16 out ----------------
__global__ __launch_bounds__(256) void ln_kernel(
    const float* __restrict__ x, const float* __restrict__ sc,
    const float* __restrict__ bi, __bf16* __restrict__ y)
{
    const size_t row = blockIdx.x;
    const int t = threadIdx.x;
    const float v = x[row * 256 + t];
    float s = v, s2 = v * v;
    #pragma unroll
    for (int o = 32; o > 0; o >>= 1) {
        s  += __shfl_xor(s, o);
        s2 += __shfl_xor(s2, o);
    }
    __shared__ float ps[4], ps2[4];
    if ((t & 63) == 0) { ps[t >> 6] = s; ps2[t >> 6] = s2; }
    __syncthreads();
    const float S  = ps[0] + ps[1] + ps[2] + ps[3];
    const float S2 = ps2[0] + ps2[1] + ps2[2] + ps2[3];
    const float mean = S * (1.0f / 256.0f);
    const float var  = S2 * (1.0f / 256.0f) - mean * mean;
    const float inv  = 1.0f / sqrtf(var + 1e-5f);
    y[row * 256 + t] = (__bf16)((v - mean) * inv * sc[t] + bi[t]);
}

__global__ __launch_bounds__(256) void ln_b16_kernel(
    const __bf16* __restrict__ x, const float* __restrict__ sc,
    const float* __restrict__ bi, __bf16* __restrict__ y)
{
    const size_t row = blockIdx.x;
    const int t = threadIdx.x;
    const float v = (float)x[row * 256 + t];
    float s = v, s2 = v * v;
    #pragma unroll
    for (int o = 32; o > 0; o >>= 1) {
        s  += __shfl_xor(s, o);
        s2 += __shfl_xor(s2, o);
    }
    __shared__ float ps[4], ps2[4];
    if ((t & 63) == 0) { ps[t >> 6] = s; ps2[t >> 6] = s2; }
    __syncthreads();
    const float S  = ps[0] + ps[1] + ps[2] + ps[3];
    const float S2 = ps2[0] + ps2[1] + ps2[2] + ps2[3];
    const float mean = S * (1.0f / 256.0f);
    const float var  = S2 * (1.0f / 256.0f) - mean * mean;
    const float inv  = 1.0f / sqrtf(var + 1e-5f);
    y[row * 256 + t] = (__bf16)((v - mean) * inv * sc[t] + bi[t]);
}

// ---------------- Batched bf16 transpose: dst[c][r] = src[r][c] ----------------
__global__ __launch_bounds__(256) void tpose_bf_kernel(
    const __bf16* __restrict__ src, __bf16* __restrict__ dst, int R, int C)
{
    const size_t bz = blockIdx.z;
    src += bz * (size_t)R * C;
    dst += bz * (size_t)R * C;
    __shared__ __bf16 tile[32][34];
    const int r0 = blockIdx.x * 32, c0 = blockIdx.y * 32;
    const int tx = threadIdx.x & 31, ty = threadIdx.x >> 5;
    #pragma unroll
    for (int i = 0; i < 32; i += 8)
        tile[ty + i][tx] = src[(size_t)(r0 + ty + i) * C + c0 + tx];
    __syncthreads();
    #pragma unroll
    for (int i = 0; i < 32; i += 8)
        dst[(size_t)(c0 + ty + i) * R + r0 + tx] = tile[tx][ty + i];
}

// ---------------- Batched cvt-transpose fp32->bf16 ----------------
__global__ __launch_bounds__(256) void tpose_cvt_kernel(
    const float* __restrict__ src, __bf16* __restrict__ dst, int R, int C)
{
    const size_t bz = blockIdx.z;
    src += bz * (size_t)R * C;
    dst += bz * (size_t)R * C;
    __shared__ __bf16 tile[32][34];
    const int r0 = blockIdx.x * 32, c0 = blockIdx.y * 32;
    const int tx = threadIdx.x & 31, ty = threadIdx.x >> 5;
    #pragma unroll
    for (int i = 0; i < 32; i += 8)
        tile[ty + i][tx] = (__bf16)src[(size_t)(r0 + ty + i) * C + c0 + tx];
    __syncthreads();
    #pragma unroll
    for (int i = 0; i < 32; i += 8)
        dst[(size_t)(c0 + ty + i) * R + r0 + tx] = tile[tx][ty + i];
}

// ---------------- MFMA bf16 GEMM: C[m,n] = sum_k A[m,k]*B[n,k] ----------------
// BM=64, BN=256, BK=32. 256 threads = 4 waves; wave w covers cols w*64..+63.
// Output offset = bb*s_b + (m>>8)*s_c + (m&255)*s_p + (n>>8)*s_w + ((n>>5)&7)*s_h + (n&31)
template<int EPI, int OBF>
__global__ __launch_bounds__(256) void mgemm_kernel(
    const __bf16* __restrict__ A, const __bf16* __restrict__ Bm, void* __restrict__ CoutV,
    int K, size_t aStride, size_t bStride,
    size_t s_b, size_t s_c, size_t s_p, size_t s_w, size_t s_h, int Mrows,
    const float* __restrict__ bias,
    const void* e0, const void* e1, const void* e2, const void* e3, const void* e4,
    float* __restrict__ rsum)
{
    const int bb = blockIdx.z;
    const int m0 = blockIdx.x * 64;
    const int n0 = blockIdx.y * 256;
    const __bf16* Ab = A + (size_t)bb * aStride;
    const __bf16* Bb = Bm + (size_t)bb * bStride;
    __shared__ __align__(16) __bf16 As[64][40];
    __shared__ __align__(16) __bf16 Bs[256][40];
    const int t = threadIdx.x;
    const int lane = t & 63;
    const int wid = t >> 6;
    const int l15 = lane & 15, lg = lane >> 4;

    f32x4 acc[4][4] = {};   // [i: m-tile][j: n-tile within wave's 64 cols]

    for (int k0 = 0; k0 < K; k0 += 32) {
        {
            const int row = t >> 2, k8 = (t & 3) << 3;
            *(bf16x8*)&As[row][k8] = *(const bf16x8*)(Ab + (size_t)(m0 + row) * K + k0 + k8);
        }
        #pragma unroll
        for (int s = 0; s < 4; ++s) {
            const int slot = s * 256 + t;
            const int row = slot >> 2, k8 = (slot & 3) << 3;
            *(bf16x8*)&Bs[row][k8] = *(const bf16x8*)(Bb + (size_t)(n0 + row) * K + k0 + k8);
        }
        __syncthreads();
        bf16x8 af[4], bfr[4];
        #pragma unroll
        for (int i = 0; i < 4; ++i)
            af[i] = *(const bf16x8*)&As[i * 16 + l15][lg * 8];
        #pragma unroll
        for (int j = 0; j < 4; ++j)
            bfr[j] = *(const bf16x8*)&Bs[wid * 64 + j * 16 + l15][lg * 8];
        #pragma unroll
        for (int i = 0; i < 4; ++i)
            #pragma unroll
            for (int j = 0; j < 4; ++j)
                acc[i][j] = __builtin_amdgcn_mfma_f32_16x16x32_bf16(af[i], bfr[j], acc[i][j], 0, 0, 0);
        __syncthreads();
    }

    const __bf16* e0b = (const __bf16*)e0;
    const float*  e1f = (const float*)e1;
    const __bf16* e2b = (const __bf16*)e2;
    const __bf16* e3b = (const __bf16*)e3;
    const __bf16* e4b = (const __bf16*)e4;
    const float*  rsf = (const float*)e0;

    #pragma unroll
    for (int i = 0; i < 4; ++i) {
        float rsm[4] = {0.f, 0.f, 0.f, 0.f};
        #pragma unroll
        for (int j = 0; j < 4; ++j) {
            const int n = n0 + wid * 64 + j * 16 + l15;
            const size_t offn = (size_t)(n >> 8) * s_w + (size_t)((n >> 5) & 7) * s_h + (n & 31);
            float bn = 0.0f;
            if (EPI == EPI_GELU || EPI == EPI_GATE || EPI == EPI_ADDRES) bn = bias[n];
            #pragma unroll
            for (int r = 0; r < 4; ++r) {
                const int m = m0 + i * 16 + lg * 4 + r;
                const size_t off = (size_t)bb * s_b + (size_t)(m >> 8) * s_c
                                 + (size_t)(m & 255) * s_p + offn;
                float v = acc[i][j][r];
                if (EPI == EPI_RELU) {
                    v = fmaxf(v, 0.0f);
                    rsm[r] += v;
                } else if (EPI == EPI_GELU) {
                    float x = v + bn;
                    v = 0.5f * x * (1.0f + erff(x * 0.7071067811865475f));
                } else if (EPI == EPI_GATE) {
                    float g = 1.0f / (1.0f + __expf(-(v + bn)));
                    float rest = e1f[off] + (float)e2b[off] + (float)e3b[off] + (float)e4b[off];
                    v = g * (float)e0b[off] + (1.0f - g) * rest;
                } else if (EPI == EPI_ADDRES) {
                    v += bn + (float)e0b[off];
                } else if (EPI == EPI_SCALE) {
                    float inv = 1.0f / fmaxf(rsf[(size_t)bb * Mrows + m], 1e-6f);
                    v = v * inv;
                }
                if (OBF) ((__bf16*)CoutV)[off] = (__bf16)v;
                else     ((float*)CoutV)[off] = v;
            }
        }
        if (EPI == EPI_RELU) {
            #pragma unroll
            for (int r = 0; r < 4; ++r) {
                float sv = rsm[r];
                sv += __shfl_xor(sv, 1);
                sv += __shfl_xor(sv, 2);
                sv += __shfl_xor(sv, 4);
                sv += __shfl_xor(sv, 8);
                if (l15 == 0) {
                    const int m = m0 + i * 16 + lg * 4 + r;
                    atomicAdd(&rsum[(size_t)bb * Mrows + m], sv);
                }
            }
        }
    }
}

// ---------------- MFMA time attention: block = (bc, 64-row p-tile) ----------------
__global__ __launch_bounds__(256) void time_attn_mfma_kernel(
    const __bf16* __restrict__ qu, const __bf16* __restrict__ qv, __bf16* __restrict__ abar)
{
    const int bc = blockIdx.x;
    const int p0 = blockIdx.y * 64;
    const __bf16* quB = qu + (size_t)bc * 65536;
    const __bf16* qvB = qv + (size_t)bc * 65536;
    __shared__ __align__(16) __bf16 Us[64][40];
    __shared__ __align__(16) __bf16 Vs[256][40];
    const int t = threadIdx.x;
    const int lane = t & 63;
    const int wid = t >> 6;
    const int l15 = lane & 15, lg = lane >> 4;

    f32x4 acc[16] = {};

    for (int h = 0; h < 8; ++h) {
        const __bf16* quH = quB + h * 8192;
        const __bf16* qvH = qvB + h * 8192;
        __syncthreads();
        {
            const int row = t >> 2, k8 = (t & 3) << 3;
            *(bf16x8*)&Us[row][k8] = *(const bf16x8*)(quH + (size_t)(p0 + row) * 32 + k8);
        }
        #pragma unroll
        for (int i = 0; i < 4; ++i) {
            const int slot = i * 256 + t;
            const int row = slot >> 2, k8 = (slot & 3) << 3;
            *(bf16x8*)&Vs[row][k8] = *(const bf16x8*)(qvH + (size_t)row * 32 + k8);
        }
        __syncthreads();

        f32x4 s[16];
        bf16x8 a = *(const bf16x8*)&Us[wid * 16 + l15][lg * 8];
        #pragma unroll
        for (int j = 0; j < 16; ++j) {
            bf16x8 bfr = *(const bf16x8*)&Vs[j * 16 + l15][lg * 8];
            s[j] = __builtin_amdgcn_mfma_f32_16x16x32_bf16(a, bfr, (f32x4){0.f, 0.f, 0.f, 0.f}, 0, 0, 0);
        }

        #pragma unroll
        for (int r = 0; r < 4; ++r) {
            float e[16];
            float sum = 0.0f;
            #pragma unroll
            for (int j = 0; j < 16; ++j) {
                e[j] = __expf(s[j][r] * INV_SQRT_R);
                sum += e[j];
            }
            sum += __shfl_xor(sum, 1);
            sum += __shfl_xor(sum, 2);
            sum += __shfl_xor(sum, 4);
            sum += __shfl_xor(sum, 8);
            const float inv = 0.125f / sum;
            #pragma unroll
            for (int j = 0; j < 16; ++j) acc[j][r] += e[j] * inv;
        }
    }

    __bf16* dst = abar + (size_t)bc * 65536 + (size_t)(p0 + wid * 16 + lg * 4) * 256 + l15;
    #pragma unroll
    for (int r = 0; r < 4; ++r)
        #pragma unroll
        for (int j = 0; j < 16; ++j)
            dst[(size_t)r * 256 + j * 16] = (__bf16)acc[j][r];
}

// ---------------- Fused channel attention + PV: one block per (b,p) ----------------
// writes m_c (bf16), no RMW
__global__ __launch_bounds__(256) void chan_fused_kernel(
    const __bf16* __restrict__ quc, const __bf16* __restrict__ qvc,
    const __bf16* __restrict__ qzn, __bf16* __restrict__ m_c)
{
    const int bp = blockIdx.x;
    const int b = bp >> 8, p = bp & 255;
    const __bf16* quB = quc + (size_t)bp * 8192;
    const __bf16* qvB = qvc + (size_t)bp * 8192;
    __shared__ float U[16896];
    __shared__ float ab[32 * 33];
    float* qus = U;
    float* qvs = U + 8448;
    const int t = threadIdx.x;
    #pragma unroll
    for (int i = 0; i < 4; ++i) {
        int fi = i * 256 + t;
        int e = fi << 3;
        bf16x8 a = *(const bf16x8*)(quB + e);
        bf16x8 bv = *(const bf16x8*)(qvB + e);
        int base = ((e >> 10) * 32 + ((e >> 5) & 31)) * 33 + (e & 31);
        #pragma unroll
        for (int j = 0; j < 8; ++j) {
            qus[base + j] = (float)a[j];
            qvs[base + j] = (float)bv[j];
        }
    }
    __syncthreads();
    const int c = t >> 3, j = t & 7;
    float acc[4] = {0.f, 0.f, 0.f, 0.f};
    for (int h = 0; h < 8; ++h) {
        float qur[32];
        #pragma unroll
        for (int r = 0; r < 32; ++r) qur[r] = qus[(h * 32 + c) * 33 + r];
        float s[4];
        #pragma unroll
        for (int jj = 0; jj < 4; ++jj) {
            int f = j * 4 + jj;
            const float* qvR = &qvs[(h * 32 + f) * 33];
            float a = 0.f;
            #pragma unroll
            for (int r = 0; r < 32; ++r) a += qur[r] * qvR[r];
            s[jj] = a * INV_SQRT_R;
        }
        float mx = fmaxf(fmaxf(s[0], s[1]), fmaxf(s[2], s[3]));
        mx = fmaxf(mx, __shfl_xor(mx, 1));
        mx = fmaxf(mx, __shfl_xor(mx, 2));
        mx = fmaxf(mx, __shfl_xor(mx, 4));
        float e0x = __expf(s[0] - mx), e1x = __expf(s[1] - mx);
        float e2x = __expf(s[2] - mx), e3x = __expf(s[3] - mx);
        float sum = e0x + e1x + e2x + e3x;
        sum += __shfl_xor(sum, 1);
        sum += __shfl_xor(sum, 2);
        sum += __shfl_xor(sum, 4);
        float inv = 0.125f / sum;
        acc[0] += e0x * inv; acc[1] += e1x * inv; acc[2] += e2x * inv; acc[3] += e3x * inv;
    }
    #pragma unroll
    for (int jj = 0; jj < 4; ++jj) ab[c * 33 + j * 4 + jj] = acc[jj];
    __syncthreads();
    float* bt = U;
    #pragma unroll 4
    for (int f = 0; f < 32; ++f)
        bt[f * 256 + t] = (float)qzn[((size_t)(b * 32 + f) * 256 + p) * 256 + t];
    __syncthreads();
    for (int c2 = 0; c2 < 32; c2 += 2) {
        float a0 = 0.f, a1 = 0.f;
        #pragma unroll
        for (int f = 0; f < 32; ++f) {
            float v = bt[f * 256 + t];
            a0 += ab[c2 * 33 + f] * v;
            a1 += ab[(c2 + 1) * 33 + f] * v;
        }
        size_t off = ((size_t)(b * 32 + c2) * 256 + p) * 256 + t;
        m_c[off] = (__bf16)a0;
        m_c[off + 65536] = (__bf16)a1;
    }
}

} // namespace

extern "C" void kernel_launch(void* const* d_in, const int* in_sizes, int n_in,
                              void* d_out, int out_size, void* d_ws, size_t ws_size,
                              hipStream_t stream)
{
    (void)in_sizes; (void)n_in; (void)out_size; (void)ws_size;
    const float* qz     = (const float*)d_in[0];
    const float* unary  = (const float*)d_in[1];
    const float* time_u = (const float*)d_in[2];
    const float* time_v = (const float*)d_in[3];
    const float* chan_u = (const float*)d_in[4];
    const float* chan_v = (const float*)d_in[5];
    const float* topic  = (const float*)d_in[6];
    const float* nsc    = (const float*)d_in[7];
    const float* nbi    = (const float*)d_in[8];
    const float* gate_w = (const float*)d_in[9];
    const float* gate_b = (const float*)d_in[10];
    const float* w1     = (const float*)d_in[11];
    const float* b1     = (const float*)d_in[12];
    const float* w2     = (const float*)d_in[13];
    const float* b2     = (const float*)d_in[14];

    // Memory map:
    //  A.lo [0,32MB):    qzn_b -> h0b
    //  A.hi [32,64MB):   weight pool (wtime, wchan, topicb, topicTb, gwb, w1b, w2b) ; rs @ +48MB
    //  B    [64,128MB):  qu_t|qv_t -> qznT -> qu_c|qv_c -> qg -> qz2 | qzb
    //  C    [128,160MB): m_t -> h1b
    //  C2   [160,192MB): m_c
    //  d_out [0,64MB):   abar -> m_g -> final fp32 out
    char* base = (char*)d_ws;
    __bf16* qzn_b  = (__bf16*)base;
    __bf16* h0b    = (__bf16*)base;
    __bf16* pool   = (__bf16*)(base + (32ull << 20));
    __bf16* wtime  = pool;                  // [b][512][256] stacked tu|tv
    __bf16* wchan  = pool + 1048576;        // [b][512][256] stacked cu|cv
    __bf16* topicb = pool + 2097152;        // [b][512][256]
    __bf16* topicTb= pool + 3145728;        // [b][256][512]
    __bf16* gwb    = pool + 4194304;
    __bf16* w1b    = pool + 4259840;
    __bf16* w2b    = pool + 4325376;
    float*  rs     = (float*)(base + (48ull << 20));   // 65536 fp32
    __bf16* B16    = (__bf16*)(base + (64ull << 20));
    __bf16* qu_t   = B16;
    __bf16* qv_t   = B16 + 16777216;
    __bf16* qznT   = B16;
    __bf16* qu_c   = B16;
    __bf16* qv_c   = B16 + 16777216;
    __bf16* qg     = B16;                   // [b][32][256][512] = 64MB
    __bf16* qz2    = B16;
    __bf16* qzb    = B16 + 16777216;
    __bf16* m_t    = (__bf16*)(base + (128ull << 20));
    __bf16* h1b    = m_t;
    __bf16* m_c    = (__bf16*)(base + (160ull << 20));
    __bf16* abar   = (__bf16*)d_out;
    __bf16* m_g    = (__bf16*)d_out;
    float*  OUTF   = (float*)d_out;

    dim3 blk(256);
    const void* np = nullptr;

    // 0) weight conversions (stacked pairs) + topic transpose
    cvt2_kernel<<<512, blk, 0, stream>>>(time_u, wtime, 524288, 131072, 0);
    cvt2_kernel<<<512, blk, 0, stream>>>(time_v, wtime, 524288, 131072, 65536);
    cvt2_kernel<<<512, blk, 0, stream>>>(chan_u, wchan, 524288, 131072, 0);
    cvt2_kernel<<<512, blk, 0, stream>>>(chan_v, wchan, 524288, 131072, 65536);
    cvt_kernel<<<1024, blk, 0, stream>>>(topic, topicb, 1048576);
    tpose_cvt_kernel<<<dim3(16, 8, 8), blk, 0, stream>>>(topic, topicTb, 512, 256);
    cvt_kernel<<<64, blk, 0, stream>>>(gate_w, gwb, 65536);
    cvt_kernel<<<64, blk, 0, stream>>>(w1, w1b, 65536);
    cvt_kernel<<<64, blk, 0, stream>>>(w2, w2b, 65536);

    // 1) qz_n = LN(qz) -> qzn_b
    ln_kernel<<<65536, blk, 0, stream>>>(qz, nsc, nbi, qzn_b);

    // 2) time projections (stacked N=512) -> qu_t | qv_t  [b][c][h][p][r]
    mgemm_kernel<EPI_NONE, 1><<<dim3(128, 2, 8), blk, 0, stream>>>(
        qzn_b, wtime, qu_t, 256, 2097152, 131072,
        2097152, 65536, 32, 16777216, 8192, 0, nullptr, np, np, np, np, np, nullptr);

    // 3) time attention -> abar (bf16, d_out)
    time_attn_mfma_kernel<<<dim3(256, 4), blk, 0, stream>>>(qu_t, qv_t, abar);

    // 4) qznT[bc][d][p] -> B.lo (qu_t dead)
    tpose_bf_kernel<<<dim3(8, 8, 256), blk, 0, stream>>>(qzn_b, qznT, 256, 256);

    // 5) m_t = abar @ qzn -> C (bf16)
    mgemm_kernel<EPI_NONE, 1><<<dim3(4, 1, 256), blk, 0, stream>>>(
        abar, qznT, m_t, 256, 65536, 65536,
        65536, 0, 256, 0, 32, 0, nullptr, np, np, np, np, np, nullptr);

    // 6) channel projections (stacked) -> qu_c | qv_c  [b][p][h][c][r]
    mgemm_kernel<EPI_NONE, 1><<<dim3(128, 2, 8), blk, 0, stream>>>(
        qzn_b, wchan, qu_c, 256, 2097152, 131072,
        2097152, 32, 8192, 16777216, 1024, 0, nullptr, np, np, np, np, np, nullptr);

    // 7) fused channel attention + PV -> m_c (bf16, C2)
    chan_fused_kernel<<<2048, blk, 0, stream>>>(qu_c, qv_c, qzn_b, m_c);

    // 8) rs = 0; topic relu GEMM with fused rowsum -> qg (B, 64MB), rs
    zero_kernel<<<256, blk, 0, stream>>>(rs, 65536);
    mgemm_kernel<EPI_RELU, 1><<<dim3(128, 2, 8), blk, 0, stream>>>(
        qzn_b, topicb, qg, 256, 2097152, 131072,
        4194304, 131072, 512, 256, 32, 8192, nullptr, np, np, np, np, np, rs);

    // 9) m_g = (qg / rs) @ topic -> d_out.lo (bf16) ; abar dead
    mgemm_kernel<EPI_SCALE, 1><<<dim3(128, 1, 8), blk, 0, stream>>>(
        qg, topicTb, m_g, 512, 4194304, 131072,
        2097152, 65536, 256, 0, 32, 8192, nullptr, rs, np, np, np, np, nullptr);

    // 10) qz -> bf16 (B.hi; qg dead)
    cvt_kernel<<<16384, blk, 0, stream>>>(qz, qzb, 16777216);

    // 11) gate combine -> qz2 (bf16, B.lo)
    mgemm_kernel<EPI_GATE, 1><<<dim3(1024, 1, 1), blk, 0, stream>>>(
        qzb, gwb, qz2, 256, 0, 0,
        0, 65536, 256, 0, 32, 0, gate_b, qzb, unary, m_t, m_c, m_g, nullptr);

    // 12) h0 = LN(qz2) -> A.lo
    ln_b16_kernel<<<65536, blk, 0, stream>>>(qz2, nsc, nbi, h0b);

    // 13) h1 = gelu(h0 @ w1 + b1) -> C (m_t dead)
    mgemm_kernel<EPI_GELU, 1><<<dim3(1024, 1, 1), blk, 0, stream>>>(
        h0b, w1b, h1b, 256, 0, 0,
        0, 65536, 256, 0, 32, 0, b1, np, np, np, np, np, nullptr);

    // 14) out = qz2 + h1 @ w2 + b2 -> d_out (fp32)
    mgemm_kernel<EPI_ADDRES, 0><<<dim3(1024, 1, 1), blk, 0, stream>>>(
        h1b, w2b, OUTF, 256, 0, 0,
        0, 65536, 256, 0, 32, 0, b2, qz2, np, np, np, np, nullptr);
}

// Round 8
// 589.346 us; speedup vs baseline: 3.5052x; 1.1575x over previous
//
#include <hip/hip_runtime.h>
#include <math.h>

namespace {

constexpr float INV_SQRT_R = 0.17677669529663689f;

typedef __attribute__((ext_vector_type(8))) __bf16 bf16x8;
typedef __attribute__((ext_vector_type(4))) float f32x4;

static __device__ __forceinline__ f32x4 MF(bf16x8 a, bf16x8 b, f32x4 c) {
    return __builtin_amdgcn_mfma_f32_16x16x32_bf16(a, b, c, 0, 0, 0);
}

// ---------------- fp32 -> bf16 elementwise ----------------
__global__ __launch_bounds__(256) void cvt_kernel(
    const float* __restrict__ src, __bf16* __restrict__ dst, int n)
{
    int i = (blockIdx.x * 256 + threadIdx.x) * 4;
    if (i < n) {
        float4 v = *(const float4*)(src + i);
        dst[i + 0] = (__bf16)v.x; dst[i + 1] = (__bf16)v.y;
        dst[i + 2] = (__bf16)v.z; dst[i + 3] = (__bf16)v.w;
    }
}

// fp32 -> bf16 with 64K-chunk restride (stacking per-batch weight pairs)
__global__ __launch_bounds__(256) void cvt2_kernel(
    const float* __restrict__ src, __bf16* __restrict__ dst, int n,
    int dstChunk, int dstOff)
{
    int i = (blockIdx.x * 256 + threadIdx.x) * 4;
    if (i < n) {
        float4 v = *(const float4*)(src + i);
        int o = (i >> 16) * dstChunk + dstOff + (i & 65535);
        dst[o + 0] = (__bf16)v.x; dst[o + 1] = (__bf16)v.y;
        dst[o + 2] = (__bf16)v.z; dst[o + 3] = (__bf16)v.w;
    }
}

// ---------------- LayerNorm over last dim (256), fp32 in, bf16 out ----------------
__global__ __launch_bounds__(256) void ln_kernel(
    const float* __restrict__ x, const float* __restrict__ sc,
    const float* __restrict__ bi, __bf16* __restrict__ y)
{
    const size_t row = blockIdx.x;
    const int t = threadIdx.x;
    const float v = x[row * 256 + t];
    float s = v, s2 = v * v;
    #pragma unroll
    for (int o = 32; o > 0; o >>= 1) {
        s  += __shfl_xor(s, o);
        s2 += __shfl_xor(s2, o);
    }
    __shared__ float ps[4], ps2[4];
    if ((t & 63) == 0) { ps[t >> 6] = s; ps2[t >> 6] = s2; }
    __syncthreads();
    const float S  = ps[0] + ps[1] + ps[2] + ps[3];
    const float S2 = ps2[0] + ps2[1] + ps2[2] + ps2[3];
    const float mean = S * (1.0f / 256.0f);
    const float var  = S2 * (1.0f / 256.0f) - mean * mean;
    const float inv  = 1.0f / sqrtf(var + 1e-5f);
    y[row * 256 + t] = (__bf16)((v - mean) * inv * sc[t] + bi[t]);
}

// ---------------- Batched bf16 transpose ----------------
__global__ __launch_bounds__(256) void tpose_bf_kernel(
    const __bf16* __restrict__ src, __bf16* __restrict__ dst, int R, int C)
{
    const size_t bz = blockIdx.z;
    src += bz * (size_t)R * C;
    dst += bz * (size_t)R * C;
    __shared__ __bf16 tile[32][34];
    const int r0 = blockIdx.x * 32, c0 = blockIdx.y * 32;
    const int tx = threadIdx.x & 31, ty = threadIdx.x >> 5;
    #pragma unroll
    for (int i = 0; i < 32; i += 8)
        tile[ty + i][tx] = src[(size_t)(r0 + ty + i) * C + c0 + tx];
    __syncthreads();
    #pragma unroll
    for (int i = 0; i < 32; i += 8)
        dst[(size_t)(c0 + ty + i) * R + r0 + tx] = tile[tx][ty + i];
}

// ---------------- Batched cvt-transpose fp32->bf16 ----------------
__global__ __launch_bounds__(256) void tpose_cvt_kernel(
    const float* __restrict__ src, __bf16* __restrict__ dst, int R, int C)
{
    const size_t bz = blockIdx.z;
    src += bz * (size_t)R * C;
    dst += bz * (size_t)R * C;
    __shared__ __bf16 tile[32][34];
    const int r0 = blockIdx.x * 32, c0 = blockIdx.y * 32;
    const int tx = threadIdx.x & 31, ty = threadIdx.x >> 5;
    #pragma unroll
    for (int i = 0; i < 32; i += 8)
        tile[ty + i][tx] = (__bf16)src[(size_t)(r0 + ty + i) * C + c0 + tx];
    __syncthreads();
    #pragma unroll
    for (int i = 0; i < 32; i += 8)
        dst[(size_t)(c0 + ty + i) * R + r0 + tx] = tile[tx][ty + i];
}

// ---------------- MFMA bf16 GEMM (plain): C[m,n] = sum_k A[m,k]*B[n,k] ----------------
// BM=64, BN=256, BK=32. bf16 out.
// Output offset = bb*s_b + (m>>8)*s_c + (m&255)*s_p + (n>>8)*s_w + ((n>>5)&7)*s_h + (n&31)
__global__ __launch_bounds__(256) void mgemm_kernel(
    const __bf16* __restrict__ A, const __bf16* __restrict__ Bm, __bf16* __restrict__ Cout,
    int K, size_t aStride, size_t bStride,
    size_t s_b, size_t s_c, size_t s_p, size_t s_w, size_t s_h)
{
    const int bb = blockIdx.z;
    const int m0 = blockIdx.x * 64;
    const int n0 = blockIdx.y * 256;
    const __bf16* Ab = A + (size_t)bb * aStride;
    const __bf16* Bb = Bm + (size_t)bb * bStride;
    __shared__ __align__(16) __bf16 As[64][40];
    __shared__ __align__(16) __bf16 Bs[256][40];
    const int t = threadIdx.x;
    const int lane = t & 63;
    const int wid = t >> 6;
    const int l15 = lane & 15, lg = lane >> 4;

    f32x4 acc[4][4] = {};

    for (int k0 = 0; k0 < K; k0 += 32) {
        {
            const int row = t >> 2, k8 = (t & 3) << 3;
            *(bf16x8*)&As[row][k8] = *(const bf16x8*)(Ab + (size_t)(m0 + row) * K + k0 + k8);
        }
        #pragma unroll
        for (int s = 0; s < 4; ++s) {
            const int slot = s * 256 + t;
            const int row = slot >> 2, k8 = (slot & 3) << 3;
            *(bf16x8*)&Bs[row][k8] = *(const bf16x8*)(Bb + (size_t)(n0 + row) * K + k0 + k8);
        }
        __syncthreads();
        bf16x8 af[4], bfr[4];
        #pragma unroll
        for (int i = 0; i < 4; ++i)
            af[i] = *(const bf16x8*)&As[i * 16 + l15][lg * 8];
        #pragma unroll
        for (int j = 0; j < 4; ++j)
            bfr[j] = *(const bf16x8*)&Bs[wid * 64 + j * 16 + l15][lg * 8];
        #pragma unroll
        for (int i = 0; i < 4; ++i)
            #pragma unroll
            for (int j = 0; j < 4; ++j)
                acc[i][j] = MF(af[i], bfr[j], acc[i][j]);
        __syncthreads();
    }

    #pragma unroll
    for (int j = 0; j < 4; ++j) {
        const int n = n0 + wid * 64 + j * 16 + l15;
        const size_t offn = (size_t)(n >> 8) * s_w + (size_t)((n >> 5) & 7) * s_h + (n & 31);
        #pragma unroll
        for (int i = 0; i < 4; ++i) {
            #pragma unroll
            for (int r = 0; r < 4; ++r) {
                const int m = m0 + i * 16 + lg * 4 + r;
                const size_t off = (size_t)bb * s_b + (size_t)(m >> 8) * s_c
                                 + (size_t)(m & 255) * s_p + offn;
                Cout[off] = (__bf16)acc[i][j][r];
            }
        }
    }
}

// ---------------- MFMA time attention: block = (bc, 64-row p-tile) ----------------
__global__ __launch_bounds__(256) void time_attn_mfma_kernel(
    const __bf16* __restrict__ qu, const __bf16* __restrict__ qv, __bf16* __restrict__ abar)
{
    const int bc = blockIdx.x;
    const int p0 = blockIdx.y * 64;
    const __bf16* quB = qu + (size_t)bc * 65536;
    const __bf16* qvB = qv + (size_t)bc * 65536;
    __shared__ __align__(16) __bf16 Us[64][40];
    __shared__ __align__(16) __bf16 Vs[256][40];
    const int t = threadIdx.x;
    const int lane = t & 63;
    const int wid = t >> 6;
    const int l15 = lane & 15, lg = lane >> 4;

    f32x4 acc[16] = {};

    for (int h = 0; h < 8; ++h) {
        const __bf16* quH = quB + h * 8192;
        const __bf16* qvH = qvB + h * 8192;
        __syncthreads();
        {
            const int row = t >> 2, k8 = (t & 3) << 3;
            *(bf16x8*)&Us[row][k8] = *(const bf16x8*)(quH + (size_t)(p0 + row) * 32 + k8);
        }
        #pragma unroll
        for (int i = 0; i < 4; ++i) {
            const int slot = i * 256 + t;
            const int row = slot >> 2, k8 = (slot & 3) << 3;
            *(bf16x8*)&Vs[row][k8] = *(const bf16x8*)(qvH + (size_t)row * 32 + k8);
        }
        __syncthreads();

        f32x4 s[16];
        bf16x8 a = *(const bf16x8*)&Us[wid * 16 + l15][lg * 8];
        #pragma unroll
        for (int j = 0; j < 16; ++j) {
            bf16x8 bfr = *(const bf16x8*)&Vs[j * 16 + l15][lg * 8];
            s[j] = MF(a, bfr, (f32x4){0.f, 0.f, 0.f, 0.f});
        }

        #pragma unroll
        for (int r = 0; r < 4; ++r) {
            float e[16];
            float sum = 0.0f;
            #pragma unroll
            for (int j = 0; j < 16; ++j) {
                e[j] = __expf(s[j][r] * INV_SQRT_R);
                sum += e[j];
            }
            sum += __shfl_xor(sum, 1);
            sum += __shfl_xor(sum, 2);
            sum += __shfl_xor(sum, 4);
            sum += __shfl_xor(sum, 8);
            const float inv = 0.125f / sum;
            #pragma unroll
            for (int j = 0; j < 16; ++j) acc[j][r] += e[j] * inv;
        }
    }

    __bf16* dst = abar + (size_t)bc * 65536 + (size_t)(p0 + wid * 16 + lg * 4) * 256 + l15;
    #pragma unroll
    for (int r = 0; r < 4; ++r)
        #pragma unroll
        for (int j = 0; j < 16; ++j)
            dst[(size_t)r * 256 + j * 16] = (__bf16)acc[j][r];
}

// ---------------- Fused channel attention + PV -> m_c (bf16) ----------------
__global__ __launch_bounds__(256) void chan_fused_kernel(
    const __bf16* __restrict__ quc, const __bf16* __restrict__ qvc,
    const __bf16* __restrict__ qzn, __bf16* __restrict__ m_c)
{
    const int bp = blockIdx.x;
    const int b = bp >> 8, p = bp & 255;
    const __bf16* quB = quc + (size_t)bp * 8192;
    const __bf16* qvB = qvc + (size_t)bp * 8192;
    __shared__ float U[16896];
    __shared__ float ab[32 * 33];
    float* qus = U;
    float* qvs = U + 8448;
    const int t = threadIdx.x;
    #pragma unroll
    for (int i = 0; i < 4; ++i) {
        int fi = i * 256 + t;
        int e = fi << 3;
        bf16x8 a = *(const bf16x8*)(quB + e);
        bf16x8 bv = *(const bf16x8*)(qvB + e);
        int base = ((e >> 10) * 32 + ((e >> 5) & 31)) * 33 + (e & 31);
        #pragma unroll
        for (int j = 0; j < 8; ++j) {
            qus[base + j] = (float)a[j];
            qvs[base + j] = (float)bv[j];
        }
    }
    __syncthreads();
    const int c = t >> 3, j = t & 7;
    float acc[4] = {0.f, 0.f, 0.f, 0.f};
    for (int h = 0; h < 8; ++h) {
        float qur[32];
        #pragma unroll
        for (int r = 0; r < 32; ++r) qur[r] = qus[(h * 32 + c) * 33 + r];
        float s[4];
        #pragma unroll
        for (int jj = 0; jj < 4; ++jj) {
            int f = j * 4 + jj;
            const float* qvR = &qvs[(h * 32 + f) * 33];
            float a = 0.f;
            #pragma unroll
            for (int r = 0; r < 32; ++r) a += qur[r] * qvR[r];
            s[jj] = a * INV_SQRT_R;
        }
        float mx = fmaxf(fmaxf(s[0], s[1]), fmaxf(s[2], s[3]));
        mx = fmaxf(mx, __shfl_xor(mx, 1));
        mx = fmaxf(mx, __shfl_xor(mx, 2));
        mx = fmaxf(mx, __shfl_xor(mx, 4));
        float e0x = __expf(s[0] - mx), e1x = __expf(s[1] - mx);
        float e2x = __expf(s[2] - mx), e3x = __expf(s[3] - mx);
        float sum = e0x + e1x + e2x + e3x;
        sum += __shfl_xor(sum, 1);
        sum += __shfl_xor(sum, 2);
        sum += __shfl_xor(sum, 4);
        float inv = 0.125f / sum;
        acc[0] += e0x * inv; acc[1] += e1x * inv; acc[2] += e2x * inv; acc[3] += e3x * inv;
    }
    #pragma unroll
    for (int jj = 0; jj < 4; ++jj) ab[c * 33 + j * 4 + jj] = acc[jj];
    __syncthreads();
    float* bt = U;
    #pragma unroll 4
    for (int f = 0; f < 32; ++f)
        bt[f * 256 + t] = (float)qzn[((size_t)(b * 32 + f) * 256 + p) * 256 + t];
    __syncthreads();
    for (int c2 = 0; c2 < 32; c2 += 2) {
        float a0 = 0.f, a1 = 0.f;
        #pragma unroll
        for (int f = 0; f < 32; ++f) {
            float v = bt[f * 256 + t];
            a0 += ab[c2 * 33 + f] * v;
            a1 += ab[(c2 + 1) * 33 + f] * v;
        }
        size_t off = ((size_t)(b * 32 + c2) * 256 + p) * 256 + t;
        m_c[off] = (__bf16)a0;
        m_c[off + 65536] = (__bf16)a1;
    }
}

// ---------------- Fused topic factor: relu-GEMM + rowsum + normalize-GEMM ----------------
// Block = 32 rows of one batch. m_g = (relu(qzn@topic^T) / rowsum) @ topic
__global__ __launch_bounds__(256, 2) void topic_fused_kernel(
    const __bf16* __restrict__ qzn, const __bf16* __restrict__ topicb,
    const __bf16* __restrict__ topicTb, __bf16* __restrict__ m_g)
{
    const int bb = blockIdx.z;
    const int m0 = blockIdx.x * 32;
    const __bf16* Ab = qzn + (size_t)bb * 2097152;    // [8192][256]
    const __bf16* B1 = topicb + (size_t)bb * 131072;  // [512][256]
    const __bf16* B2 = topicTb + (size_t)bb * 131072; // [256][512]
    __shared__ __align__(16) __bf16 As[32][40];
    __shared__ __align__(16) __bf16 Bs[512][40];
    __shared__ __align__(16) __bf16 Ps[32][520];
    __shared__ float rsInv[32];
    const int t = threadIdx.x;
    const int lane = t & 63, wid = t >> 6;
    const int l15 = lane & 15, lg = lane >> 4;

    // GEMM1: qg[32][512] = A @ B1^T, K=256. Wave w covers cols w*128..+127.
    f32x4 acc[2][8] = {};
    for (int k0 = 0; k0 < 256; k0 += 32) {
        if (t < 128) {
            const int row = t >> 2, k8 = (t & 3) << 3;
            *(bf16x8*)&As[row][k8] = *(const bf16x8*)(Ab + (size_t)(m0 + row) * 256 + k0 + k8);
        }
        #pragma unroll
        for (int s = 0; s < 8; ++s) {
            const int slot = s * 256 + t;
            const int row = slot >> 2, k8 = (slot & 3) << 3;
            *(bf16x8*)&Bs[row][k8] = *(const bf16x8*)(B1 + (size_t)row * 256 + k0 + k8);
        }
        __syncthreads();
        bf16x8 af0 = *(const bf16x8*)&As[l15][lg * 8];
        bf16x8 af1 = *(const bf16x8*)&As[16 + l15][lg * 8];
        #pragma unroll
        for (int j = 0; j < 8; ++j) {
            bf16x8 b8 = *(const bf16x8*)&Bs[wid * 128 + j * 16 + l15][lg * 8];
            acc[0][j] = MF(af0, b8, acc[0][j]);
            acc[1][j] = MF(af1, b8, acc[1][j]);
        }
        __syncthreads();
    }
    // relu -> Ps (bf16)
    #pragma unroll
    for (int i = 0; i < 2; ++i)
        #pragma unroll
        for (int j = 0; j < 8; ++j) {
            const int n = wid * 128 + j * 16 + l15;
            #pragma unroll
            for (int r = 0; r < 4; ++r)
                Ps[i * 16 + lg * 4 + r][n] = (__bf16)fmaxf(acc[i][j][r], 0.0f);
        }
    __syncthreads();
    // rowsum: 32 rows x 8 segments of 64
    {
        const int row = t >> 3, seg = t & 7;
        float s = 0.0f;
        #pragma unroll
        for (int u = 0; u < 8; ++u) {
            bf16x8 v = *(const bf16x8*)&Ps[row][seg * 64 + u * 8];
            #pragma unroll
            for (int e = 0; e < 8; ++e) s += (float)v[e];
        }
        s += __shfl_xor(s, 1);
        s += __shfl_xor(s, 2);
        s += __shfl_xor(s, 4);
        if (seg == 0) rsInv[row] = 1.0f / fmaxf(s, 1e-6f);
    }
    __syncthreads();
    // GEMM2: m_g[32][256] = Ps @ B2^T, K=512; scale rows by rsInv in epilogue.
    f32x4 acc2[2][4] = {};
    for (int k0 = 0; k0 < 512; k0 += 32) {
        #pragma unroll
        for (int s = 0; s < 4; ++s) {
            const int slot = s * 256 + t;
            const int row = slot >> 2, k8 = (slot & 3) << 3;
            *(bf16x8*)&Bs[row][k8] = *(const bf16x8*)(B2 + (size_t)row * 512 + k0 + k8);
        }
        __syncthreads();
        bf16x8 af0 = *(const bf16x8*)&Ps[l15][k0 + lg * 8];
        bf16x8 af1 = *(const bf16x8*)&Ps[16 + l15][k0 + lg * 8];
        #pragma unroll
        for (int j = 0; j < 4; ++j) {
            bf16x8 b8 = *(const bf16x8*)&Bs[wid * 64 + j * 16 + l15][lg * 8];
            acc2[0][j] = MF(af0, b8, acc2[0][j]);
            acc2[1][j] = MF(af1, b8, acc2[1][j]);
        }
        __syncthreads();
    }
    #pragma unroll
    for (int i = 0; i < 2; ++i)
        #pragma unroll
        for (int j = 0; j < 4; ++j) {
            const int n = wid * 64 + j * 16 + l15;
            #pragma unroll
            for (int r = 0; r < 4; ++r) {
                const int ml = i * 16 + lg * 4 + r;
                m_g[(size_t)bb * 2097152 + (size_t)(m0 + ml) * 256 + n]
                    = (__bf16)(acc2[i][j][r] * rsInv[ml]);
            }
        }
}

// ---------------- Mega: gate-GEMM + combine + LN + MLP (2 GEMMs) + residual ----------------
// Block = 64 rows (full N=256). qz2 lives in registers; h0/h1 in LDS.
__global__ __launch_bounds__(256, 2) void mega_kernel(
    const __bf16* __restrict__ qzb, const float* __restrict__ unary,
    const __bf16* __restrict__ m_t, const __bf16* __restrict__ m_c,
    const __bf16* __restrict__ m_g,
    const __bf16* __restrict__ gwb, const float* __restrict__ gate_b,
    const __bf16* __restrict__ w1b, const float* __restrict__ b1,
    const __bf16* __restrict__ w2b, const float* __restrict__ b2,
    const float* __restrict__ nsc, const float* __restrict__ nbi,
    float* __restrict__ outp)
{
    const int m0 = blockIdx.x * 64;
    __shared__ __align__(16) __bf16 As[64][40];
    __shared__ __align__(16) __bf16 Bs[256][40];
    __shared__ __align__(16) __bf16 hL[64][264];
    __shared__ float lnp[64][4][2];
    const int t = threadIdx.x;
    const int lane = t & 63, wid = t >> 6;
    const int l15 = lane & 15, lg = lane >> 4;

    // ---- GEMM1: gate logits = qzb @ gwb^T ----
    f32x4 acc[4][4] = {};
    for (int k0 = 0; k0 < 256; k0 += 32) {
        {
            const int row = t >> 2, k8 = (t & 3) << 3;
            *(bf16x8*)&As[row][k8] = *(const bf16x8*)(qzb + (size_t)(m0 + row) * 256 + k0 + k8);
        }
        #pragma unroll
        for (int s = 0; s < 4; ++s) {
            const int slot = s * 256 + t;
            const int row = slot >> 2, k8 = (slot & 3) << 3;
            *(bf16x8*)&Bs[row][k8] = *(const bf16x8*)(gwb + (size_t)row * 256 + k0 + k8);
        }
        __syncthreads();
        bf16x8 af[4], bfr[4];
        #pragma unroll
        for (int i = 0; i < 4; ++i) af[i] = *(const bf16x8*)&As[i * 16 + l15][lg * 8];
        #pragma unroll
        for (int j = 0; j < 4; ++j) bfr[j] = *(const bf16x8*)&Bs[wid * 64 + j * 16 + l15][lg * 8];
        #pragma unroll
        for (int i = 0; i < 4; ++i)
            #pragma unroll
            for (int j = 0; j < 4; ++j)
                acc[i][j] = MF(af[i], bfr[j], acc[i][j]);
        __syncthreads();
    }

    // ---- combine -> qz2 (registers) + LN partials ----
    f32x4 z2[4][4];
    #pragma unroll
    for (int i = 0; i < 4; ++i) {
        #pragma unroll
        for (int r = 0; r < 4; ++r) {
            float s = 0.0f, s2 = 0.0f;
            #pragma unroll
            for (int j = 0; j < 4; ++j) {
                const int n = wid * 64 + j * 16 + l15;
                const size_t off = (size_t)(m0 + i * 16 + lg * 4 + r) * 256 + n;
                float g = 1.0f / (1.0f + __expf(-(acc[i][j][r] + gate_b[n])));
                float rest = unary[off] + (float)m_t[off] + (float)m_c[off] + (float)m_g[off];
                float v = g * (float)qzb[off] + (1.0f - g) * rest;
                z2[i][j][r] = v;
                s += v; s2 += v * v;
            }
            s  += __shfl_xor(s, 1);  s  += __shfl_xor(s, 2);
            s  += __shfl_xor(s, 4);  s  += __shfl_xor(s, 8);
            s2 += __shfl_xor(s2, 1); s2 += __shfl_xor(s2, 2);
            s2 += __shfl_xor(s2, 4); s2 += __shfl_xor(s2, 8);
            if (l15 == 0) {
                lnp[i * 16 + lg * 4 + r][wid][0] = s;
                lnp[i * 16 + lg * 4 + r][wid][1] = s2;
            }
        }
    }
    __syncthreads();
    // ---- h0 = LN(qz2) -> hL ----
    #pragma unroll
    for (int i = 0; i < 4; ++i) {
        #pragma unroll
        for (int r = 0; r < 4; ++r) {
            const int rr = i * 16 + lg * 4 + r;
            float S  = lnp[rr][0][0] + lnp[rr][1][0] + lnp[rr][2][0] + lnp[rr][3][0];
            float S2 = lnp[rr][0][1] + lnp[rr][1][1] + lnp[rr][2][1] + lnp[rr][3][1];
            float mean = S * (1.0f / 256.0f);
            float var  = S2 * (1.0f / 256.0f) - mean * mean;
            float inv  = 1.0f / sqrtf(var + 1e-5f);
            #pragma unroll
            for (int j = 0; j < 4; ++j) {
                const int n = wid * 64 + j * 16 + l15;
                hL[rr][n] = (__bf16)((z2[i][j][r] - mean) * inv * nsc[n] + nbi[n]);
            }
        }
    }
    __syncthreads();

    // ---- GEMM2: h1 = gelu(h0 @ w1^T + b1) ----
    f32x4 acc2[4][4] = {};
    for (int k0 = 0; k0 < 256; k0 += 32) {
        #pragma unroll
        for (int s = 0; s < 4; ++s) {
            const int slot = s * 256 + t;
            const int row = slot >> 2, k8 = (slot & 3) << 3;
            *(bf16x8*)&Bs[row][k8] = *(const bf16x8*)(w1b + (size_t)row * 256 + k0 + k8);
        }
        __syncthreads();
        bf16x8 af[4], bfr[4];
        #pragma unroll
        for (int i = 0; i < 4; ++i) af[i] = *(const bf16x8*)&hL[i * 16 + l15][k0 + lg * 8];
        #pragma unroll
        for (int j = 0; j < 4; ++j) bfr[j] = *(const bf16x8*)&Bs[wid * 64 + j * 16 + l15][lg * 8];
        #pragma unroll
        for (int i = 0; i < 4; ++i)
            #pragma unroll
            for (int j = 0; j < 4; ++j)
                acc2[i][j] = MF(af[i], bfr[j], acc2[i][j]);
        __syncthreads();
    }
    // h1 -> hL (all h0 reads complete after last barrier)
    #pragma unroll
    for (int i = 0; i < 4; ++i)
        #pragma unroll
        for (int j = 0; j < 4; ++j) {
            const int n = wid * 64 + j * 16 + l15;
            const float bn = b1[n];
            #pragma unroll
            for (int r = 0; r < 4; ++r) {
                float x = acc2[i][j][r] + bn;
                hL[i * 16 + lg * 4 + r][n] = (__bf16)(0.5f * x * (1.0f + erff(x * 0.7071067811865475f)));
            }
        }
    __syncthreads();

    // ---- GEMM3: out = qz2 + h1 @ w2^T + b2 ----
    f32x4 acc3[4][4] = {};
    for (int k0 = 0; k0 < 256; k0 += 32) {
        #pragma unroll
        for (int s = 0; s < 4; ++s) {
            const int slot = s * 256 + t;
            const int row = slot >> 2, k8 = (slot & 3) << 3;
            *(bf16x8*)&Bs[row][k8] = *(const bf16x8*)(w2b + (size_t)row * 256 + k0 + k8);
        }
        __syncthreads();
        bf16x8 af[4], bfr[4];
        #pragma unroll
        for (int i = 0; i < 4; ++i) af[i] = *(const bf16x8*)&hL[i * 16 + l15][k0 + lg * 8];
        #pragma unroll
        for (int j = 0; j < 4; ++j) bfr[j] = *(const bf16x8*)&Bs[wid * 64 + j * 16 + l15][lg * 8];
        #pragma unroll
        for (int i = 0; i < 4; ++i)
            #pragma unroll
            for (int j = 0; j < 4; ++j)
                acc3[i][j] = MF(af[i], bfr[j], acc3[i][j]);
        __syncthreads();
    }
    #pragma unroll
    for (int i = 0; i < 4; ++i)
        #pragma unroll
        for (int j = 0; j < 4; ++j) {
            const int n = wid * 64 + j * 16 + l15;
            const float bn = b2[n];
            #pragma unroll
            for (int r = 0; r < 4; ++r) {
                const size_t off = (size_t)(m0 + i * 16 + lg * 4 + r) * 256 + n;
                outp[off] = z2[i][j][r] + acc3[i][j][r] + bn;
            }
        }
}

} // namespace

extern "C" void kernel_launch(void* const* d_in, const int* in_sizes, int n_in,
                              void* d_out, int out_size, void* d_ws, size_t ws_size,
                              hipStream_t stream)
{
    (void)in_sizes; (void)n_in; (void)out_size; (void)ws_size;
    const float* qz     = (const float*)d_in[0];
    const float* unary  = (const float*)d_in[1];
    const float* time_u = (const float*)d_in[2];
    const float* time_v = (const float*)d_in[3];
    const float* chan_u = (const float*)d_in[4];
    const float* chan_v = (const float*)d_in[5];
    const float* topic  = (const float*)d_in[6];
    const float* nsc    = (const float*)d_in[7];
    const float* nbi    = (const float*)d_in[8];
    const float* gate_w = (const float*)d_in[9];
    const float* gate_b = (const float*)d_in[10];
    const float* w1     = (const float*)d_in[11];
    const float* b1     = (const float*)d_in[12];
    const float* w2     = (const float*)d_in[13];
    const float* b2     = (const float*)d_in[14];

    // Memory map (192MB d_ws + 64MB d_out):
    //  A.lo [0,32MB):    qzn_b (live through topic_fused)
    //  A.hi [32,64MB):   weight pool
    //  B.lo [64,96MB):   qu_t -> qznT -> qu_c -> qzb
    //  B.hi [96,128MB):  qv_t -> qv_c -> m_g
    //  C1  [128,160MB):  m_t
    //  C2  [160,192MB):  m_c
    //  d_out:            abar (scratch) -> final fp32 out
    char* base = (char*)d_ws;
    __bf16* qzn_b  = (__bf16*)base;
    __bf16* pool   = (__bf16*)(base + (32ull << 20));
    __bf16* wtime  = pool;                  // [b][512][256] stacked tu|tv
    __bf16* wchan  = pool + 1048576;        // [b][512][256] stacked cu|cv
    __bf16* topicb = pool + 2097152;        // [b][512][256]
    __bf16* topicTb= pool + 3145728;        // [b][256][512]
    __bf16* gwb    = pool + 4194304;
    __bf16* w1b    = pool + 4259840;
    __bf16* w2b    = pool + 4325376;
    __bf16* Blo    = (__bf16*)(base + (64ull << 20));
    __bf16* Bhi    = (__bf16*)(base + (96ull << 20));
    __bf16* qu_t   = Blo;
    __bf16* qv_t   = Bhi;
    __bf16* qznT   = Blo;
    __bf16* qu_c   = Blo;
    __bf16* qv_c   = Bhi;
    __bf16* qzb    = Blo;
    __bf16* m_g    = Bhi;
    __bf16* m_t    = (__bf16*)(base + (128ull << 20));
    __bf16* m_c    = (__bf16*)(base + (160ull << 20));
    __bf16* abar   = (__bf16*)d_out;
    float*  OUTF   = (float*)d_out;

    dim3 blk(256);

    // 0) weight conversions (stacked pairs) + topic transpose
    cvt2_kernel<<<512, blk, 0, stream>>>(time_u, wtime, 524288, 131072, 0);
    cvt2_kernel<<<512, blk, 0, stream>>>(time_v, wtime, 524288, 131072, 65536);
    cvt2_kernel<<<512, blk, 0, stream>>>(chan_u, wchan, 524288, 131072, 0);
    cvt2_kernel<<<512, blk, 0, stream>>>(chan_v, wchan, 524288, 131072, 65536);
    cvt_kernel<<<1024, blk, 0, stream>>>(topic, topicb, 1048576);
    tpose_cvt_kernel<<<dim3(16, 8, 8), blk, 0, stream>>>(topic, topicTb, 512, 256);
    cvt_kernel<<<64, blk, 0, stream>>>(gate_w, gwb, 65536);
    cvt_kernel<<<64, blk, 0, stream>>>(w1, w1b, 65536);
    cvt_kernel<<<64, blk, 0, stream>>>(w2, w2b, 65536);

    // 1) qz_n = LN(qz) -> qzn_b
    ln_kernel<<<65536, blk, 0, stream>>>(qz, nsc, nbi, qzn_b);

    // 2) time projections (stacked N=512) -> qu_t | qv_t  [b][c][h][p][r]
    mgemm_kernel<<<dim3(128, 2, 8), blk, 0, stream>>>(
        qzn_b, wtime, qu_t, 256, 2097152, 131072,
        2097152, 65536, 32, 16777216, 8192);

    // 3) time attention -> abar (bf16, d_out scratch)
    time_attn_mfma_kernel<<<dim3(256, 4), blk, 0, stream>>>(qu_t, qv_t, abar);

    // 4) qznT[bc][d][p] -> B.lo (qu_t dead)
    tpose_bf_kernel<<<dim3(8, 8, 256), blk, 0, stream>>>(qzn_b, qznT, 256, 256);

    // 5) m_t = abar @ qznT -> C1
    mgemm_kernel<<<dim3(4, 1, 256), blk, 0, stream>>>(
        abar, qznT, m_t, 256, 65536, 65536,
        65536, 0, 256, 0, 32);

    // 6) channel projections (stacked) -> qu_c | qv_c  [b][p][h][c][r]
    mgemm_kernel<<<dim3(128, 2, 8), blk, 0, stream>>>(
        qzn_b, wchan, qu_c, 256, 2097152, 131072,
        2097152, 32, 8192, 16777216, 1024);

    // 7) fused channel attention + PV -> m_c
    chan_fused_kernel<<<2048, blk, 0, stream>>>(qu_c, qv_c, qzn_b, m_c);

    // 8) fused topic factor -> m_g (B.hi; qv_c dead)
    topic_fused_kernel<<<dim3(256, 1, 8), blk, 0, stream>>>(qzn_b, topicb, topicTb, m_g);

    // 9) qz -> bf16 (B.lo; qu_c dead)
    cvt_kernel<<<16384, blk, 0, stream>>>(qz, qzb, 16777216);

    // 10) mega: gate + combine + LN + MLP + residual -> d_out (fp32)
    mega_kernel<<<1024, blk, 0, stream>>>(
        qzb, unary, m_t, m_c, m_g,
        gwb, gate_b, w1b, b1, w2b, b2, nsc, nbi, OUTF);
}

// Round 9
// 540.723 us; speedup vs baseline: 3.8204x; 1.0899x over previous
//
#include <hip/hip_runtime.h>
#include <math.h>

namespace {

constexpr float INV_SQRT_R = 0.17677669529663689f;

typedef __attribute__((ext_vector_type(8))) __bf16 bf16x8;
typedef __attribute__((ext_vector_type(4))) float f32x4;

static __device__ __forceinline__ f32x4 MF(bf16x8 a, bf16x8 b, f32x4 c) {
    return __builtin_amdgcn_mfma_f32_16x16x32_bf16(a, b, c, 0, 0, 0);
}

// ---------------- fp32 -> bf16 elementwise ----------------
__global__ __launch_bounds__(256) void cvt_kernel(
    const float* __restrict__ src, __bf16* __restrict__ dst, int n)
{
    int i = (blockIdx.x * 256 + threadIdx.x) * 4;
    if (i < n) {
        float4 v = *(const float4*)(src + i);
        dst[i + 0] = (__bf16)v.x; dst[i + 1] = (__bf16)v.y;
        dst[i + 2] = (__bf16)v.z; dst[i + 3] = (__bf16)v.w;
    }
}

// fp32 -> bf16 with 64K-chunk restride (stacking per-batch weight pairs)
__global__ __launch_bounds__(256) void cvt2_kernel(
    const float* __restrict__ src, __bf16* __restrict__ dst, int n,
    int dstChunk, int dstOff)
{
    int i = (blockIdx.x * 256 + threadIdx.x) * 4;
    if (i < n) {
        float4 v = *(const float4*)(src + i);
        int o = (i >> 16) * dstChunk + dstOff + (i & 65535);
        dst[o + 0] = (__bf16)v.x; dst[o + 1] = (__bf16)v.y;
        dst[o + 2] = (__bf16)v.z; dst[o + 3] = (__bf16)v.w;
    }
}

// ---------------- LayerNorm over last dim (256), fp32 in, bf16 out ----------------
__global__ __launch_bounds__(256) void ln_kernel(
    const float* __restrict__ x, const float* __restrict__ sc,
    const float* __restrict__ bi, __bf16* __restrict__ y)
{
    const size_t row = blockIdx.x;
    const int t = threadIdx.x;
    const float v = x[row * 256 + t];
    float s = v, s2 = v * v;
    #pragma unroll
    for (int o = 32; o > 0; o >>= 1) {
        s  += __shfl_xor(s, o);
        s2 += __shfl_xor(s2, o);
    }
    __shared__ float ps[4], ps2[4];
    if ((t & 63) == 0) { ps[t >> 6] = s; ps2[t >> 6] = s2; }
    __syncthreads();
    const float S  = ps[0] + ps[1] + ps[2] + ps[3];
    const float S2 = ps2[0] + ps2[1] + ps2[2] + ps2[3];
    const float mean = S * (1.0f / 256.0f);
    const float var  = S2 * (1.0f / 256.0f) - mean * mean;
    const float inv  = 1.0f / sqrtf(var + 1e-5f);
    y[row * 256 + t] = (__bf16)((v - mean) * inv * sc[t] + bi[t]);
}

// ---------------- Batched bf16 transpose ----------------
__global__ __launch_bounds__(256) void tpose_bf_kernel(
    const __bf16* __restrict__ src, __bf16* __restrict__ dst, int R, int C)
{
    const size_t bz = blockIdx.z;
    src += bz * (size_t)R * C;
    dst += bz * (size_t)R * C;
    __shared__ __bf16 tile[32][34];
    const int r0 = blockIdx.x * 32, c0 = blockIdx.y * 32;
    const int tx = threadIdx.x & 31, ty = threadIdx.x >> 5;
    #pragma unroll
    for (int i = 0; i < 32; i += 8)
        tile[ty + i][tx] = src[(size_t)(r0 + ty + i) * C + c0 + tx];
    __syncthreads();
    #pragma unroll
    for (int i = 0; i < 32; i += 8)
        dst[(size_t)(c0 + ty + i) * R + r0 + tx] = tile[tx][ty + i];
}

// ---------------- Batched cvt-transpose fp32->bf16 ----------------
__global__ __launch_bounds__(256) void tpose_cvt_kernel(
    const float* __restrict__ src, __bf16* __restrict__ dst, int R, int C)
{
    const size_t bz = blockIdx.z;
    src += bz * (size_t)R * C;
    dst += bz * (size_t)R * C;
    __shared__ __bf16 tile[32][34];
    const int r0 = blockIdx.x * 32, c0 = blockIdx.y * 32;
    const int tx = threadIdx.x & 31, ty = threadIdx.x >> 5;
    #pragma unroll
    for (int i = 0; i < 32; i += 8)
        tile[ty + i][tx] = (__bf16)src[(size_t)(r0 + ty + i) * C + c0 + tx];
    __syncthreads();
    #pragma unroll
    for (int i = 0; i < 32; i += 8)
        dst[(size_t)(c0 + ty + i) * R + r0 + tx] = tile[tx][ty + i];
}

// ---------------- MFMA bf16 GEMM (projections): C[m,n]=sum_k A[m,k]*B[n,k] ----------------
// BM=64, BN=256. Output offset = bb*s_b + (m&255)*s_p + (m>>8)*s_c + (n>>8)*s_w + ((n>>5)&7)*s_h + (n&31)
__global__ __launch_bounds__(256) void mgemm_kernel(
    const __bf16* __restrict__ A, const __bf16* __restrict__ Bm, __bf16* __restrict__ Cout,
    int K, size_t aStride, size_t bStride,
    size_t s_b, size_t s_c, size_t s_p, size_t s_w, size_t s_h)
{
    const int bb = blockIdx.z;
    const int m0 = blockIdx.x * 64;
    const int n0 = blockIdx.y * 256;
    const __bf16* Ab = A + (size_t)bb * aStride;
    const __bf16* Bb = Bm + (size_t)bb * bStride;
    __shared__ __align__(16) __bf16 As[64][40];
    __shared__ __align__(16) __bf16 Bs[256][40];
    const int t = threadIdx.x;
    const int lane = t & 63;
    const int wid = t >> 6;
    const int l15 = lane & 15, lg = lane >> 4;

    f32x4 acc[4][4] = {};

    for (int k0 = 0; k0 < K; k0 += 32) {
        {
            const int row = t >> 2, k8 = (t & 3) << 3;
            *(bf16x8*)&As[row][k8] = *(const bf16x8*)(Ab + (size_t)(m0 + row) * K + k0 + k8);
        }
        #pragma unroll
        for (int s = 0; s < 4; ++s) {
            const int slot = s * 256 + t;
            const int row = slot >> 2, k8 = (slot & 3) << 3;
            *(bf16x8*)&Bs[row][k8] = *(const bf16x8*)(Bb + (size_t)(n0 + row) * K + k0 + k8);
        }
        __syncthreads();
        bf16x8 af[4], bfr[4];
        #pragma unroll
        for (int i = 0; i < 4; ++i)
            af[i] = *(const bf16x8*)&As[i * 16 + l15][lg * 8];
        #pragma unroll
        for (int j = 0; j < 4; ++j)
            bfr[j] = *(const bf16x8*)&Bs[wid * 64 + j * 16 + l15][lg * 8];
        #pragma unroll
        for (int i = 0; i < 4; ++i)
            #pragma unroll
            for (int j = 0; j < 4; ++j)
                acc[i][j] = MF(af[i], bfr[j], acc[i][j]);
        __syncthreads();
    }

    #pragma unroll
    for (int j = 0; j < 4; ++j) {
        const int n = n0 + wid * 64 + j * 16 + l15;
        const size_t offn = (size_t)(n >> 8) * s_w + (size_t)((n >> 5) & 7) * s_h + (n & 31);
        #pragma unroll
        for (int i = 0; i < 4; ++i) {
            #pragma unroll
            for (int r = 0; r < 4; ++r) {
                const int m = m0 + i * 16 + lg * 4 + r;
                const size_t off = (size_t)bb * s_b + (size_t)(m >> 8) * s_c
                                 + (size_t)(m & 255) * s_p + offn;
                Cout[off] = (__bf16)acc[i][j][r];
            }
        }
    }
}

// ---------------- Fused time attention + PV: block = (bc, 64-row p-tile) ----------------
// qu/qv [bc][h][p][r]; qznT [bc][d][q]; writes m_t[bc][p][d] = Abar @ qznT^T directly.
__global__ __launch_bounds__(256) void time_attn_mt_kernel(
    const __bf16* __restrict__ qu, const __bf16* __restrict__ qv,
    const __bf16* __restrict__ qznT, __bf16* __restrict__ m_t)
{
    const int bc = blockIdx.x;
    const int p0 = blockIdx.y * 64;
    const __bf16* quB = qu + (size_t)bc * 65536;
    const __bf16* qvB = qv + (size_t)bc * 65536;
    const __bf16* BT  = qznT + (size_t)bc * 65536;
    // Phase A: Us [64][40] @0, Vs [256][40] @2560. Phase B: aL [64][264] @0, Bs2 [256][40] @16896.
    __shared__ __align__(16) __bf16 R1[27136];
    __bf16* Us  = R1;
    __bf16* Vs  = R1 + 2560;
    __bf16* aL  = R1;
    __bf16* Bs2 = R1 + 16896;
    const int t = threadIdx.x;
    const int lane = t & 63;
    const int wid = t >> 6;
    const int l15 = lane & 15, lg = lane >> 4;

    f32x4 acc[16] = {};   // head-averaged probs: rows wid*16+lg*4+r, cols j*16+l15

    for (int h = 0; h < 8; ++h) {
        const __bf16* quH = quB + h * 8192;
        const __bf16* qvH = qvB + h * 8192;
        __syncthreads();
        {
            const int row = t >> 2, k8 = (t & 3) << 3;
            *(bf16x8*)&Us[row * 40 + k8] = *(const bf16x8*)(quH + (size_t)(p0 + row) * 32 + k8);
        }
        #pragma unroll
        for (int i = 0; i < 4; ++i) {
            const int slot = i * 256 + t;
            const int row = slot >> 2, k8 = (slot & 3) << 3;
            *(bf16x8*)&Vs[row * 40 + k8] = *(const bf16x8*)(qvH + (size_t)row * 32 + k8);
        }
        __syncthreads();

        f32x4 s[16];
        bf16x8 a = *(const bf16x8*)&Us[(wid * 16 + l15) * 40 + lg * 8];
        #pragma unroll
        for (int j = 0; j < 16; ++j) {
            bf16x8 bfr = *(const bf16x8*)&Vs[(j * 16 + l15) * 40 + lg * 8];
            s[j] = MF(a, bfr, (f32x4){0.f, 0.f, 0.f, 0.f});
        }

        #pragma unroll
        for (int r = 0; r < 4; ++r) {
            float e[16];
            float sum = 0.0f;
            #pragma unroll
            for (int j = 0; j < 16; ++j) {
                e[j] = __expf(s[j][r] * INV_SQRT_R);
                sum += e[j];
            }
            sum += __shfl_xor(sum, 1);
            sum += __shfl_xor(sum, 2);
            sum += __shfl_xor(sum, 4);
            sum += __shfl_xor(sum, 8);
            const float inv = 0.125f / sum;
            #pragma unroll
            for (int j = 0; j < 16; ++j) acc[j][r] += e[j] * inv;
        }
    }

    // ---- Abar -> LDS (bf16 [64][264]) ----
    __syncthreads();   // all Vs/Us reads done before overwrite
    #pragma unroll
    for (int r = 0; r < 4; ++r) {
        const int row = wid * 16 + lg * 4 + r;
        #pragma unroll
        for (int j = 0; j < 16; ++j)
            aL[row * 264 + j * 16 + l15] = (__bf16)acc[j][r];
    }
    __syncthreads();

    // ---- GEMM2: m_t[p][d] = Abar[p][q] @ qznT[d][q], K=256 ----
    f32x4 acc2[4][4] = {};
    for (int k0 = 0; k0 < 256; k0 += 32) {
        #pragma unroll
        for (int s = 0; s < 4; ++s) {
            const int slot = s * 256 + t;
            const int row = slot >> 2, k8 = (slot & 3) << 3;
            *(bf16x8*)&Bs2[row * 40 + k8] = *(const bf16x8*)(BT + (size_t)row * 256 + k0 + k8);
        }
        __syncthreads();
        bf16x8 af[4], bfr[4];
        #pragma unroll
        for (int i = 0; i < 4; ++i)
            af[i] = *(const bf16x8*)&aL[(i * 16 + l15) * 264 + k0 + lg * 8];
        #pragma unroll
        for (int j = 0; j < 4; ++j)
            bfr[j] = *(const bf16x8*)&Bs2[(wid * 64 + j * 16 + l15) * 40 + lg * 8];
        #pragma unroll
        for (int i = 0; i < 4; ++i)
            #pragma unroll
            for (int j = 0; j < 4; ++j)
                acc2[i][j] = MF(af[i], bfr[j], acc2[i][j]);
        __syncthreads();
    }
    #pragma unroll
    for (int i = 0; i < 4; ++i)
        #pragma unroll
        for (int j = 0; j < 4; ++j) {
            const int d = wid * 64 + j * 16 + l15;
            #pragma unroll
            for (int r = 0; r < 4; ++r) {
                const int p = p0 + i * 16 + lg * 4 + r;
                m_t[(size_t)bc * 65536 + (size_t)p * 256 + d] = (__bf16)acc2[i][j][r];
            }
        }
}

// ---------------- Fused channel attention + PV -> m_c (bf16) ----------------
// bf16 LDS (45KB -> 3 blocks/CU)
__global__ __launch_bounds__(256) void chan_fused_kernel(
    const __bf16* __restrict__ quc, const __bf16* __restrict__ qvc,
    const __bf16* __restrict__ qzn, __bf16* __restrict__ m_c)
{
    const int bp = blockIdx.x;
    const int b = bp >> 8, p = bp & 255;
    const __bf16* quB = quc + (size_t)bp * 8192;
    const __bf16* qvB = qvc + (size_t)bp * 8192;
    __shared__ __align__(16) __bf16 QU[20480];   // qus[8][32][40] + qvs[8][32][40]; later bt[32][256] f32
    __shared__ float ab[32 * 33];
    __bf16* qus = QU;
    __bf16* qvs = QU + 10240;
    const int t = threadIdx.x;
    #pragma unroll
    for (int i = 0; i < 4; ++i) {
        int fi = i * 256 + t;
        int e = fi << 3;
        int h = e >> 10, cc = (e >> 5) & 31, r = e & 31;
        int base = (h * 32 + cc) * 40 + r;
        *(bf16x8*)&qus[base] = *(const bf16x8*)(quB + e);
        *(bf16x8*)&qvs[base] = *(const bf16x8*)(qvB + e);
    }
    __syncthreads();
    const int c = t >> 3, j = t & 7;
    float acc[4] = {0.f, 0.f, 0.f, 0.f};
    for (int h = 0; h < 8; ++h) {
        float qur[32];
        #pragma unroll
        for (int u = 0; u < 4; ++u) {
            bf16x8 q8 = *(const bf16x8*)&qus[(h * 32 + c) * 40 + u * 8];
            #pragma unroll
            for (int e2 = 0; e2 < 8; ++e2) qur[u * 8 + e2] = (float)q8[e2];
        }
        float s[4];
        #pragma unroll
        for (int jj = 0; jj < 4; ++jj) {
            int f = j * 4 + jj;
            float a = 0.f;
            #pragma unroll
            for (int u = 0; u < 4; ++u) {
                bf16x8 v8 = *(const bf16x8*)&qvs[(h * 32 + f) * 40 + u * 8];
                #pragma unroll
                for (int e2 = 0; e2 < 8; ++e2) a += qur[u * 8 + e2] * (float)v8[e2];
            }
            s[jj] = a * INV_SQRT_R;
        }
        float mx = fmaxf(fmaxf(s[0], s[1]), fmaxf(s[2], s[3]));
        mx = fmaxf(mx, __shfl_xor(mx, 1));
        mx = fmaxf(mx, __shfl_xor(mx, 2));
        mx = fmaxf(mx, __shfl_xor(mx, 4));
        float e0x = __expf(s[0] - mx), e1x = __expf(s[1] - mx);
        float e2x = __expf(s[2] - mx), e3x = __expf(s[3] - mx);
        float sum = e0x + e1x + e2x + e3x;
        sum += __shfl_xor(sum, 1);
        sum += __shfl_xor(sum, 2);
        sum += __shfl_xor(sum, 4);
        float inv = 0.125f / sum;
        acc[0] += e0x * inv; acc[1] += e1x * inv; acc[2] += e2x * inv; acc[3] += e3x * inv;
    }
    #pragma unroll
    for (int jj = 0; jj < 4; ++jj) ab[c * 33 + j * 4 + jj] = acc[jj];
    __syncthreads();
    float* bt = (float*)QU;   // 32KB <= 40KB region
    #pragma unroll 4
    for (int f = 0; f < 32; ++f)
        bt[f * 256 + t] = (float)qzn[((size_t)(b * 32 + f) * 256 + p) * 256 + t];
    __syncthreads();
    for (int c2 = 0; c2 < 32; c2 += 2) {
        float a0 = 0.f, a1 = 0.f;
        #pragma unroll
        for (int f = 0; f < 32; ++f) {
            float v = bt[f * 256 + t];
            a0 += ab[c2 * 33 + f] * v;
            a1 += ab[(c2 + 1) * 33 + f] * v;
        }
        size_t off = ((size_t)(b * 32 + c2) * 256 + p) * 256 + t;
        m_c[off] = (__bf16)a0;
        m_c[off + 65536] = (__bf16)a1;
    }
}

// ---------------- Fused topic factor: relu-GEMM + rowsum + normalize-GEMM ----------------
__global__ __launch_bounds__(256, 2) void topic_fused_kernel(
    const __bf16* __restrict__ qzn, const __bf16* __restrict__ topicb,
    const __bf16* __restrict__ topicTb, __bf16* __restrict__ m_g)
{
    const int bb = blockIdx.z;
    const int m0 = blockIdx.x * 32;
    const __bf16* Ab = qzn + (size_t)bb * 2097152;
    const __bf16* B1 = topicb + (size_t)bb * 131072;
    const __bf16* B2 = topicTb + (size_t)bb * 131072;
    __shared__ __align__(16) __bf16 As[32][40];
    __shared__ __align__(16) __bf16 Bs[512][40];
    __shared__ __align__(16) __bf16 Ps[32][520];
    __shared__ float rsInv[32];
    const int t = threadIdx.x;
    const int lane = t & 63, wid = t >> 6;
    const int l15 = lane & 15, lg = lane >> 4;

    f32x4 acc[2][8] = {};
    for (int k0 = 0; k0 < 256; k0 += 32) {
        if (t < 128) {
            const int row = t >> 2, k8 = (t & 3) << 3;
            *(bf16x8*)&As[row][k8] = *(const bf16x8*)(Ab + (size_t)(m0 + row) * 256 + k0 + k8);
        }
        #pragma unroll
        for (int s = 0; s < 8; ++s) {
            const int slot = s * 256 + t;
            const int row = slot >> 2, k8 = (slot & 3) << 3;
            *(bf16x8*)&Bs[row][k8] = *(const bf16x8*)(B1 + (size_t)row * 256 + k0 + k8);
        }
        __syncthreads();
        bf16x8 af0 = *(const bf16x8*)&As[l15][lg * 8];
        bf16x8 af1 = *(const bf16x8*)&As[16 + l15][lg * 8];
        #pragma unroll
        for (int j = 0; j < 8; ++j) {
            bf16x8 b8 = *(const bf16x8*)&Bs[wid * 128 + j * 16 + l15][lg * 8];
            acc[0][j] = MF(af0, b8, acc[0][j]);
            acc[1][j] = MF(af1, b8, acc[1][j]);
        }
        __syncthreads();
    }
    #pragma unroll
    for (int i = 0; i < 2; ++i)
        #pragma unroll
        for (int j = 0; j < 8; ++j) {
            const int n = wid * 128 + j * 16 + l15;
            #pragma unroll
            for (int r = 0; r < 4; ++r)
                Ps[i * 16 + lg * 4 + r][n] = (__bf16)fmaxf(acc[i][j][r], 0.0f);
        }
    __syncthreads();
    {
        const int row = t >> 3, seg = t & 7;
        float s = 0.0f;
        #pragma unroll
        for (int u = 0; u < 8; ++u) {
            bf16x8 v = *(const bf16x8*)&Ps[row][seg * 64 + u * 8];
            #pragma unroll
            for (int e = 0; e < 8; ++e) s += (float)v[e];
        }
        s += __shfl_xor(s, 1);
        s += __shfl_xor(s, 2);
        s += __shfl_xor(s, 4);
        if (seg == 0) rsInv[row] = 1.0f / fmaxf(s, 1e-6f);
    }
    __syncthreads();
    f32x4 acc2[2][4] = {};
    for (int k0 = 0; k0 < 512; k0 += 32) {
        #pragma unroll
        for (int s = 0; s < 4; ++s) {
            const int slot = s * 256 + t;
            const int row = slot >> 2, k8 = (slot & 3) << 3;
            *(bf16x8*)&Bs[row][k8] = *(const bf16x8*)(B2 + (size_t)row * 512 + k0 + k8);
        }
        __syncthreads();
        bf16x8 af0 = *(const bf16x8*)&Ps[l15][k0 + lg * 8];
        bf16x8 af1 = *(const bf16x8*)&Ps[16 + l15][k0 + lg * 8];
        #pragma unroll
        for (int j = 0; j < 4; ++j) {
            bf16x8 b8 = *(const bf16x8*)&Bs[wid * 64 + j * 16 + l15][lg * 8];
            acc2[0][j] = MF(af0, b8, acc2[0][j]);
            acc2[1][j] = MF(af1, b8, acc2[1][j]);
        }
        __syncthreads();
    }
    #pragma unroll
    for (int i = 0; i < 2; ++i)
        #pragma unroll
        for (int j = 0; j < 4; ++j) {
            const int n = wid * 64 + j * 16 + l15;
            #pragma unroll
            for (int r = 0; r < 4; ++r) {
                const int ml = i * 16 + lg * 4 + r;
                m_g[(size_t)bb * 2097152 + (size_t)(m0 + ml) * 256 + n]
                    = (__bf16)(acc2[i][j][r] * rsInv[ml]);
            }
        }
}

// ---------------- Mega: qz-cvt + gate-GEMM + combine + LN + MLP + residual ----------------
// Block = 64 rows. qz staged fp32->bf16 into hL (A of GEMM1 + combine source); qz2 in regs.
__global__ __launch_bounds__(256, 2) void mega_kernel(
    const float* __restrict__ qz, const float* __restrict__ unary,
    const __bf16* __restrict__ m_t, const __bf16* __restrict__ m_c,
    const __bf16* __restrict__ m_g,
    const __bf16* __restrict__ gwb, const float* __restrict__ gate_b,
    const __bf16* __restrict__ w1b, const float* __restrict__ b1,
    const __bf16* __restrict__ w2b, const float* __restrict__ b2,
    const float* __restrict__ nsc, const float* __restrict__ nbi,
    float* __restrict__ outp)
{
    const int m0 = blockIdx.x * 64;
    __shared__ __align__(16) __bf16 Bs[256][40];
    __shared__ __align__(16) __bf16 hL[64][264];   // qzb -> h0 -> h1
    __shared__ float lnp[64][4][2];
    const int t = threadIdx.x;
    const int lane = t & 63, wid = t >> 6;
    const int l15 = lane & 15, lg = lane >> 4;

    // ---- stage qz (fp32 -> bf16) into hL ----
    #pragma unroll
    for (int s = 0; s < 8; ++s) {
        const int slot = s * 256 + t;             // 0..2047
        const int row = slot >> 5;                // 0..63
        const int k8 = (slot & 31) << 3;          // 0..248
        const float* src = qz + (size_t)(m0 + row) * 256 + k8;
        float4 v0 = *(const float4*)src;
        float4 v1 = *(const float4*)(src + 4);
        bf16x8 pk;
        pk[0] = (__bf16)v0.x; pk[1] = (__bf16)v0.y; pk[2] = (__bf16)v0.z; pk[3] = (__bf16)v0.w;
        pk[4] = (__bf16)v1.x; pk[5] = (__bf16)v1.y; pk[6] = (__bf16)v1.z; pk[7] = (__bf16)v1.w;
        *(bf16x8*)&hL[row][k8] = pk;
    }

    // ---- GEMM1: gate logits = qzb @ gwb^T (A from hL) ----
    f32x4 acc[4][4] = {};
    for (int k0 = 0; k0 < 256; k0 += 32) {
        #pragma unroll
        for (int s = 0; s < 4; ++s) {
            const int slot = s * 256 + t;
            const int row = slot >> 2, k8 = (slot & 3) << 3;
            *(bf16x8*)&Bs[row][k8] = *(const bf16x8*)(gwb + (size_t)row * 256 + k0 + k8);
        }
        __syncthreads();
        bf16x8 af[4], bfr[4];
        #pragma unroll
        for (int i = 0; i < 4; ++i) af[i] = *(const bf16x8*)&hL[i * 16 + l15][k0 + lg * 8];
        #pragma unroll
        for (int j = 0; j < 4; ++j) bfr[j] = *(const bf16x8*)&Bs[wid * 64 + j * 16 + l15][lg * 8];
        #pragma unroll
        for (int i = 0; i < 4; ++i)
            #pragma unroll
            for (int j = 0; j < 4; ++j)
                acc[i][j] = MF(af[i], bfr[j], acc[i][j]);
        __syncthreads();
    }

    // ---- combine -> qz2 (registers) + LN partials; qzb read from hL ----
    f32x4 z2[4][4];
    #pragma unroll
    for (int i = 0; i < 4; ++i) {
        #pragma unroll
        for (int r = 0; r < 4; ++r) {
            const int rr = i * 16 + lg * 4 + r;
            float s = 0.0f, s2 = 0.0f;
            #pragma unroll
            for (int j = 0; j < 4; ++j) {
                const int n = wid * 64 + j * 16 + l15;
                const size_t off = (size_t)(m0 + rr) * 256 + n;
                float g = 1.0f / (1.0f + __expf(-(acc[i][j][r] + gate_b[n])));
                float rest = unary[off] + (float)m_t[off] + (float)m_c[off] + (float)m_g[off];
                float v = g * (float)hL[rr][n] + (1.0f - g) * rest;
                z2[i][j][r] = v;
                s += v; s2 += v * v;
            }
            s  += __shfl_xor(s, 1);  s  += __shfl_xor(s, 2);
            s  += __shfl_xor(s, 4);  s  += __shfl_xor(s, 8);
            s2 += __shfl_xor(s2, 1); s2 += __shfl_xor(s2, 2);
            s2 += __shfl_xor(s2, 4); s2 += __shfl_xor(s2, 8);
            if (l15 == 0) {
                lnp[rr][wid][0] = s;
                lnp[rr][wid][1] = s2;
            }
        }
    }
    __syncthreads();
    // ---- h0 = LN(qz2) -> hL ----
    #pragma unroll
    for (int i = 0; i < 4; ++i) {
        #pragma unroll
        for (int r = 0; r < 4; ++r) {
            const int rr = i * 16 + lg * 4 + r;
            float S  = lnp[rr][0][0] + lnp[rr][1][0] + lnp[rr][2][0] + lnp[rr][3][0];
            float S2 = lnp[rr][0][1] + lnp[rr][1][1] + lnp[rr][2][1] + lnp[rr][3][1];
            float mean = S * (1.0f / 256.0f);
            float var  = S2 * (1.0f / 256.0f) - mean * mean;
            float inv  = 1.0f / sqrtf(var + 1e-5f);
            #pragma unroll
            for (int j = 0; j < 4; ++j) {
                const int n = wid * 64 + j * 16 + l15;
                hL[rr][n] = (__bf16)((z2[i][j][r] - mean) * inv * nsc[n] + nbi[n]);
            }
        }
    }
    __syncthreads();

    // ---- GEMM2: h1 = gelu(h0 @ w1^T + b1) ----
    f32x4 acc2[4][4] = {};
    for (int k0 = 0; k0 < 256; k0 += 32) {
        #pragma unroll
        for (int s = 0; s < 4; ++s) {
            const int slot = s * 256 + t;
            const int row = slot >> 2, k8 = (slot & 3) << 3;
            *(bf16x8*)&Bs[row][k8] = *(const bf16x8*)(w1b + (size_t)row * 256 + k0 + k8);
        }
        __syncthreads();
        bf16x8 af[4], bfr[4];
        #pragma unroll
        for (int i = 0; i < 4; ++i) af[i] = *(const bf16x8*)&hL[i * 16 + l15][k0 + lg * 8];
        #pragma unroll
        for (int j = 0; j < 4; ++j) bfr[j] = *(const bf16x8*)&Bs[wid * 64 + j * 16 + l15][lg * 8];
        #pragma unroll
        for (int i = 0; i < 4; ++i)
            #pragma unroll
            for (int j = 0; j < 4; ++j)
                acc2[i][j] = MF(af[i], bfr[j], acc2[i][j]);
        __syncthreads();
    }
    #pragma unroll
    for (int i = 0; i < 4; ++i)
        #pragma unroll
        for (int j = 0; j < 4; ++j) {
            const int n = wid * 64 + j * 16 + l15;
            const float bn = b1[n];
            #pragma unroll
            for (int r = 0; r < 4; ++r) {
                float x = acc2[i][j][r] + bn;
                hL[i * 16 + lg * 4 + r][n] = (__bf16)(0.5f * x * (1.0f + erff(x * 0.7071067811865475f)));
            }
        }
    __syncthreads();

    // ---- GEMM3: out = qz2 + h1 @ w2^T + b2 ----
    f32x4 acc3[4][4] = {};
    for (int k0 = 0; k0 < 256; k0 += 32) {
        #pragma unroll
        for (int s = 0; s < 4; ++s) {
            const int slot = s * 256 + t;
            const int row = slot >> 2, k8 = (slot & 3) << 3;
            *(bf16x8*)&Bs[row][k8] = *(const bf16x8*)(w2b + (size_t)row * 256 + k0 + k8);
        }
        __syncthreads();
        bf16x8 af[4], bfr[4];
        #pragma unroll
        for (int i = 0; i < 4; ++i) af[i] = *(const bf16x8*)&hL[i * 16 + l15][k0 + lg * 8];
        #pragma unroll
        for (int j = 0; j < 4; ++j) bfr[j] = *(const bf16x8*)&Bs[wid * 64 + j * 16 + l15][lg * 8];
        #pragma unroll
        for (int i = 0; i < 4; ++i)
            #pragma unroll
            for (int j = 0; j < 4; ++j)
                acc3[i][j] = MF(af[i], bfr[j], acc3[i][j]);
        __syncthreads();
    }
    #pragma unroll
    for (int i = 0; i < 4; ++i)
        #pragma unroll
        for (int j = 0; j < 4; ++j) {
            const int n = wid * 64 + j * 16 + l15;
            const float bn = b2[n];
            #pragma unroll
            for (int r = 0; r < 4; ++r) {
                const size_t off = (size_t)(m0 + i * 16 + lg * 4 + r) * 256 + n;
                outp[off] = z2[i][j][r] + acc3[i][j][r] + bn;
            }
        }
}

} // namespace

extern "C" void kernel_launch(void* const* d_in, const int* in_sizes, int n_in,
                              void* d_out, int out_size, void* d_ws, size_t ws_size,
                              hipStream_t stream)
{
    (void)in_sizes; (void)n_in; (void)out_size; (void)ws_size;
    const float* qz     = (const float*)d_in[0];
    const float* unary  = (const float*)d_in[1];
    const float* time_u = (const float*)d_in[2];
    const float* time_v = (const float*)d_in[3];
    const float* chan_u = (const float*)d_in[4];
    const float* chan_v = (const float*)d_in[5];
    const float* topic  = (const float*)d_in[6];
    const float* nsc    = (const float*)d_in[7];
    const float* nbi    = (const float*)d_in[8];
    const float* gate_w = (const float*)d_in[9];
    const float* gate_b = (const float*)d_in[10];
    const float* w1     = (const float*)d_in[11];
    const float* b1     = (const float*)d_in[12];
    const float* w2     = (const float*)d_in[13];
    const float* b2     = (const float*)d_in[14];

    // Memory map (192MB d_ws):
    //  A.lo [0,32MB):   qzn_b (live through topic_fused)
    //  A.hi [32,64MB):  weight pool
    //  Blo [64,96MB):   qu_t -> qu_c -> m_g
    //  Bhi [96,128MB):  qv_t -> qv_c
    //  C1  [128,160MB): qznT -> m_c
    //  C2  [160,192MB): m_t
    //  d_out: final fp32 out only
    char* base = (char*)d_ws;
    __bf16* qzn_b  = (__bf16*)base;
    __bf16* pool   = (__bf16*)(base + (32ull << 20));
    __bf16* wtime  = pool;
    __bf16* wchan  = pool + 1048576;
    __bf16* topicb = pool + 2097152;
    __bf16* topicTb= pool + 3145728;
    __bf16* gwb    = pool + 4194304;
    __bf16* w1b    = pool + 4259840;
    __bf16* w2b    = pool + 4325376;
    __bf16* Blo    = (__bf16*)(base + (64ull << 20));
    __bf16* Bhi    = (__bf16*)(base + (96ull << 20));
    __bf16* qu_t   = Blo;
    __bf16* qv_t   = Bhi;
    __bf16* qu_c   = Blo;
    __bf16* qv_c   = Bhi;
    __bf16* m_g    = Blo;
    __bf16* qznT   = (__bf16*)(base + (128ull << 20));
    __bf16* m_c    = qznT;
    __bf16* m_t    = (__bf16*)(base + (160ull << 20));
    float*  OUTF   = (float*)d_out;

    dim3 blk(256);

    // 0) weight conversions + topic transpose
    cvt2_kernel<<<512, blk, 0, stream>>>(time_u, wtime, 524288, 131072, 0);
    cvt2_kernel<<<512, blk, 0, stream>>>(time_v, wtime, 524288, 131072, 65536);
    cvt2_kernel<<<512, blk, 0, stream>>>(chan_u, wchan, 524288, 131072, 0);
    cvt2_kernel<<<512, blk, 0, stream>>>(chan_v, wchan, 524288, 131072, 65536);
    cvt_kernel<<<1024, blk, 0, stream>>>(topic, topicb, 1048576);
    tpose_cvt_kernel<<<dim3(16, 8, 8), blk, 0, stream>>>(topic, topicTb, 512, 256);
    cvt_kernel<<<64, blk, 0, stream>>>(gate_w, gwb, 65536);
    cvt_kernel<<<64, blk, 0, stream>>>(w1, w1b, 65536);
    cvt_kernel<<<64, blk, 0, stream>>>(w2, w2b, 65536);

    // 1) qz_n = LN(qz) -> qzn_b ; qznT -> C1
    ln_kernel<<<65536, blk, 0, stream>>>(qz, nsc, nbi, qzn_b);
    tpose_bf_kernel<<<dim3(8, 8, 256), blk, 0, stream>>>(qzn_b, qznT, 256, 256);

    // 2) time projections (stacked N=512) -> qu_t | qv_t  [b][c][h][p][r]
    mgemm_kernel<<<dim3(128, 2, 8), blk, 0, stream>>>(
        qzn_b, wtime, qu_t, 256, 2097152, 131072,
        2097152, 65536, 32, 16777216, 8192);

    // 3) fused time attention + PV -> m_t (C2)
    time_attn_mt_kernel<<<dim3(256, 4), blk, 0, stream>>>(qu_t, qv_t, qznT, m_t);

    // 4) channel projections (stacked) -> qu_c | qv_c  [b][p][h][c][r]
    mgemm_kernel<<<dim3(128, 2, 8), blk, 0, stream>>>(
        qzn_b, wchan, qu_c, 256, 2097152, 131072,
        2097152, 32, 8192, 16777216, 1024);

    // 5) fused channel attention + PV -> m_c (C1; qznT dead)
    chan_fused_kernel<<<2048, blk, 0, stream>>>(qu_c, qv_c, qzn_b, m_c);

    // 6) fused topic factor -> m_g (Blo; qu_c dead)
    topic_fused_kernel<<<dim3(256, 1, 8), blk, 0, stream>>>(qzn_b, topicb, topicTb, m_g);

    // 7) mega: qz-cvt + gate + combine + LN + MLP + residual -> d_out (fp32)
    mega_kernel<<<1024, blk, 0, stream>>>(
        qz, unary, m_t, m_c, m_g,
        gwb, gate_b, w1b, b1, w2b, b2, nsc, nbi, OUTF);
}